// Round 10
// baseline (242.096 us; speedup 1.0000x reference)
//
#include <hip/hip_runtime.h>
#include <hip/hip_bf16.h>

#define I_LEN 512
#define BSZ   8
#define HIDN  1024
#define NHEAD 16
#define HDIM  64
#define PLEN_ 1024
#define SCALE_F 0.125f
#define BIGNUM 1e30f
#define LN_EPS 1e-5f

typedef unsigned int   u32;
typedef unsigned short u16;
typedef __attribute__((ext_vector_type(8))) short bf16x8;
typedef __attribute__((ext_vector_type(4))) float f32x4;

__device__ __forceinline__ float bflo(u32 w) { return __uint_as_float(w << 16); }
__device__ __forceinline__ float bfhi(u32 w) { return __uint_as_float(w & 0xffff0000u); }
__device__ __forceinline__ u16 f2bf(float x) {
  u32 u = __float_as_uint(x);
  return (u16)((u + 0x7fffu + ((u >> 16) & 1u)) >> 16);
}
__device__ __forceinline__ void bf8_to_f(const uint4 v, float* f) {
  f[0] = bflo(v.x); f[1] = bfhi(v.x);
  f[2] = bflo(v.y); f[3] = bfhi(v.y);
  f[4] = bflo(v.z); f[5] = bfhi(v.z);
  f[6] = bflo(v.w); f[7] = bfhi(v.w);
}

#define GLOAD_LDS16(gp, lp) __builtin_amdgcn_global_load_lds( \
    (const __attribute__((address_space(1))) void*)(gp),      \
    (__attribute__((address_space(3))) void*)(lp), 16, 0, 0)

// ---------------- fused projection GEMM: 5-way z (Q,K,V from Hb bf16; Kr 2 halves f32) --
// z==2 (V) writes directly in transposed Vt2[bn][i>>6][d][i&63] layout.
__global__ __launch_bounds__(256)
void proj_gemm(const u16* __restrict__ Hb, const float* __restrict__ pos,
               const u16* __restrict__ Wqt, const u16* __restrict__ Wkt,
               const u16* __restrict__ Wvt, const u16* __restrict__ Wrt,
               u16* __restrict__ Qh, u16* __restrict__ Kh,
               u16* __restrict__ Vt2, u16* __restrict__ Krh) {
  constexpr int K = 1024;
  __shared__ union {
    struct { u16 As[128 * 64]; u16 Bs[128 * 64]; } st;
    u16 epi[4][64 * 68];
  } sm;
  u16* As = sm.st.As;
  u16* Bs = sm.st.Bs;
  const int z = blockIdx.z;
  const u16* Bt; u16* C; int MH, rowoff;
  if (z == 0)      { Bt = Wqt; C = Qh;  MH = 512;  rowoff = 0; }
  else if (z == 1) { Bt = Wkt; C = Kh;  MH = 512;  rowoff = 0; }
  else if (z == 2) { Bt = Wvt; C = Vt2; MH = 512;  rowoff = 0; }
  else if (z == 3) { Bt = Wrt; C = Krh; MH = 1024; rowoff = 0; }
  else             { Bt = Wrt; C = Krh; MH = 1024; rowoff = 4096; }
  const float* Apos = pos + (size_t)rowoff * 1024;
  const int bm = blockIdx.y * 128, bn = blockIdx.x * 128;
  const int tid = threadIdx.x, wv = tid >> 6, lane = tid & 63;
  const int l15 = lane & 15, g = lane >> 4;
  const int wr = wv >> 1, wc = wv & 1;

  f32x4 acc[4][4];
#pragma unroll
  for (int m = 0; m < 4; ++m)
#pragma unroll
    for (int n = 0; n < 4; ++n) acc[m][n] = (f32x4){0.f, 0.f, 0.f, 0.f};

  for (int k0 = 0; k0 < K; k0 += 64) {
#pragma unroll
    for (int p = 0; p < 4; ++p) {
      const int unit = (wv * 4 + p) * 64 + lane;
      const int row = unit >> 3, up = unit & 7, c = up ^ (row & 7);
      GLOAD_LDS16(&Bt[(size_t)(bn + row) * K + k0 + c * 8], &Bs[unit * 8]);
    }
    if (z < 3) {
#pragma unroll
      for (int p = 0; p < 4; ++p) {
        const int unit = (wv * 4 + p) * 64 + lane;
        const int row = unit >> 3, up = unit & 7, c = up ^ (row & 7);
        GLOAD_LDS16(&Hb[(size_t)(bm + row) * K + k0 + c * 8], &As[unit * 8]);
      }
    } else {
#pragma unroll
      for (int p = 0; p < 4; ++p) {
        const int unit = p * 256 + tid;
        const int row = unit >> 3, up = unit & 7, c = up ^ (row & 7);
        const float* src = &Apos[(size_t)(bm + row) * K + k0 + c * 8];
        const float4 f0 = *(const float4*)src;
        const float4 f1 = *(const float4*)(src + 4);
        ushort4 h0, h1;
        h0.x = f2bf(f0.x); h0.y = f2bf(f0.y); h0.z = f2bf(f0.z); h0.w = f2bf(f0.w);
        h1.x = f2bf(f1.x); h1.y = f2bf(f1.y); h1.z = f2bf(f1.z); h1.w = f2bf(f1.w);
        *(ushort4*)&As[unit * 8] = h0;
        *(ushort4*)&As[unit * 8 + 4] = h1;
      }
    }
    __syncthreads();
#pragma unroll
    for (int h = 0; h < 2; ++h) {
      bf16x8 af[4], bfv[4];
#pragma unroll
      for (int m = 0; m < 4; ++m) {
        const int row = wr * 64 + m * 16 + l15;
        af[m] = *(const bf16x8*)&As[row * 64 + ((h * 4 + g) ^ (row & 7)) * 8];
      }
#pragma unroll
      for (int n = 0; n < 4; ++n) {
        const int col = wc * 64 + n * 16 + l15;
        bfv[n] = *(const bf16x8*)&Bs[col * 64 + ((h * 4 + g) ^ (col & 7)) * 8];
      }
#pragma unroll
      for (int m = 0; m < 4; ++m)
#pragma unroll
        for (int n = 0; n < 4; ++n)
          acc[m][n] = __builtin_amdgcn_mfma_f32_16x16x32_bf16(af[m], bfv[n], acc[m][n], 0, 0, 0);
    }
    __syncthreads();
  }
  u16* slice = sm.epi[wv];
  __syncthreads();
#pragma unroll
  for (int m = 0; m < 4; ++m)
#pragma unroll
    for (int nf = 0; nf < 4; ++nf)
#pragma unroll
      for (int r = 0; r < 4; ++r)
        slice[(m * 16 + g * 4 + r) * 68 + nf * 16 + l15] = f2bf(acc[m][nf][r]);
  if (z == 2) {
    const int n = (bn + wc * 64) >> 6;
    const int rb = bm + wr * 64;
    const int ibase = rb >> 3;
    const int iblk = ibase >> 6;
    const int ilo = ibase & 63;
    const int d = lane;
#pragma unroll
    for (int b_ = 0; b_ < 8; ++b_) {
      union { u16 us[8]; uint4 q; } o;
#pragma unroll
      for (int e = 0; e < 8; ++e) o.us[e] = slice[(e * 8 + b_) * 68 + d];
      *(uint4*)&C[((((size_t)(b_ * 16 + n)) * 8 + iblk) * 64 + d) * 64 + ilo] = o.q;
    }
  } else {
#pragma unroll
    for (int it = 0; it < 8; ++it) {
      const int rl = it * 8 + (lane >> 3);
      const int cl = (lane & 7) * 8;
      const ushort4 a = *(const ushort4*)&slice[rl * 68 + cl];
      const ushort4 b2 = *(const ushort4*)&slice[rl * 68 + cl + 4];
      const int row = rowoff + bm + wr * 64 + rl;
      const int col = bn + wc * 64 + cl;
      const size_t idx = ((size_t)((row & 7) * 16 + (col >> 6)) * MH + (row >> 3)) * 64 + (col & 63);
      *(ushort4*)&C[idx] = a;
      *(ushort4*)&C[idx + 4] = b2;
    }
  }
}

// ---------------- O-projection GEMM: 64x128 tile, A bf16, B=Wob bf16, C f32 + residual --
__global__ __launch_bounds__(256)
void oproj_gemm(const u16* __restrict__ A, const u16* __restrict__ Wob,
                const float* __restrict__ Res, float* __restrict__ C) {
  constexpr int K = 1024;
  __shared__ u16 As[64 * 64];
  __shared__ u16 Bs[128 * 64];
  const int bm = blockIdx.y * 64, bn = blockIdx.x * 128;
  const int tid = threadIdx.x, wv = tid >> 6, lane = tid & 63;
  const int l15 = lane & 15, g = lane >> 4;
  const int wr = wv >> 1, wc = wv & 1;

  f32x4 acc[2][4];
#pragma unroll
  for (int m = 0; m < 2; ++m)
#pragma unroll
    for (int n = 0; n < 4; ++n) acc[m][n] = (f32x4){0.f, 0.f, 0.f, 0.f};

  for (int k0 = 0; k0 < K; k0 += 64) {
#pragma unroll
    for (int p = 0; p < 2; ++p) {
      const int unit = (wv * 2 + p) * 64 + lane;
      const int row = unit >> 3, up = unit & 7, c = up ^ (row & 7);
      GLOAD_LDS16(&A[(size_t)(bm + row) * K + k0 + c * 8], &As[unit * 8]);
    }
#pragma unroll
    for (int p = 0; p < 4; ++p) {
      const int unit = (wv * 4 + p) * 64 + lane;
      const int row = unit >> 3, up = unit & 7, c = up ^ (row & 7);
      GLOAD_LDS16(&Wob[(size_t)(bn + row) * K + k0 + c * 8], &Bs[unit * 8]);
    }
    __syncthreads();
#pragma unroll
    for (int h = 0; h < 2; ++h) {
      bf16x8 af[2], bfv[4];
#pragma unroll
      for (int m = 0; m < 2; ++m) {
        const int row = wr * 32 + m * 16 + l15;
        af[m] = *(const bf16x8*)&As[row * 64 + ((h * 4 + g) ^ (row & 7)) * 8];
      }
#pragma unroll
      for (int n = 0; n < 4; ++n) {
        const int col = wc * 64 + n * 16 + l15;
        bfv[n] = *(const bf16x8*)&Bs[col * 64 + ((h * 4 + g) ^ (col & 7)) * 8];
      }
#pragma unroll
      for (int m = 0; m < 2; ++m)
#pragma unroll
        for (int n = 0; n < 4; ++n)
          acc[m][n] = __builtin_amdgcn_mfma_f32_16x16x32_bf16(af[m], bfv[n], acc[m][n], 0, 0, 0);
    }
    __syncthreads();
  }
#pragma unroll
  for (int m = 0; m < 2; ++m) {
    const int row0 = bm + wr * 32 + m * 16 + g * 4;
#pragma unroll
    for (int nf = 0; nf < 4; ++nf) {
      const int col = bn + wc * 64 + nf * 16 + l15;
#pragma unroll
      for (int r = 0; r < 4; ++r) {
        const int row = row0 + r;
        C[(size_t)row * 1024 + col] = acc[m][nf][r] + Res[(size_t)row * 1024 + col];
      }
    }
  }
}

// ---------------- hidden + ow f32 -> bf16 ----------------
__global__ __launch_bounds__(256)
void hcvt_kernel(const float* __restrict__ hidden, const float* __restrict__ ow,
                 u16* __restrict__ Hb, u16* __restrict__ Wob) {
  const size_t i = (size_t)blockIdx.x * 256 + threadIdx.x;
  const float* src; u16* dst; size_t off;
  if (i < 524288) { src = hidden; dst = Hb; off = i * 8; }
  else            { src = ow;     dst = Wob; off = (i - 524288) * 8; }
  const float4 a = *(const float4*)&src[off];
  const float4 b = *(const float4*)&src[off + 4];
  ushort4 o0, o1;
  o0.x = f2bf(a.x); o0.y = f2bf(a.y); o0.z = f2bf(a.z); o0.w = f2bf(a.w);
  o1.x = f2bf(b.x); o1.y = f2bf(b.y); o1.z = f2bf(b.z); o1.w = f2bf(b.w);
  *(ushort4*)&dst[off] = o0;
  *(ushort4*)&dst[off + 4] = o1;
}

// ---------------- weight transpose+cvt: W[h][nd] f32 -> T[nd][h] bf16 ----------------
__global__ __launch_bounds__(256)
void wtrans_kernel(const float* __restrict__ W0, const float* __restrict__ W1,
                   const float* __restrict__ W2, const float* __restrict__ W3,
                   u16* __restrict__ T0, u16* __restrict__ T1,
                   u16* __restrict__ T2, u16* __restrict__ T3) {
  __shared__ u16 tile[64][72];
  const int z = blockIdx.z;
  const float* W = (z == 0) ? W0 : ((z == 1) ? W1 : ((z == 2) ? W2 : W3));
  u16* T = (z == 0) ? T0 : ((z == 1) ? T1 : ((z == 2) ? T2 : T3));
  const int h0 = blockIdx.y * 64, nd0 = blockIdx.x * 64;
  const int t = threadIdx.x;
  {
    const int hr = t >> 2, c0 = (t & 3) * 16;
#pragma unroll
    for (int q = 0; q < 4; ++q) {
      const float4 f = *(const float4*)&W[(size_t)(h0 + hr) * 1024 + nd0 + c0 + q * 4];
      tile[hr][c0 + q * 4 + 0] = f2bf(f.x);
      tile[hr][c0 + q * 4 + 1] = f2bf(f.y);
      tile[hr][c0 + q * 4 + 2] = f2bf(f.z);
      tile[hr][c0 + q * 4 + 3] = f2bf(f.w);
    }
  }
  __syncthreads();
  const int ndr = t >> 2, hc0 = (t & 3) * 16;
  union { u16 us[16]; uint4 qv[2]; } o;
#pragma unroll
  for (int e = 0; e < 16; ++e) o.us[e] = tile[hc0 + e][ndr];
  uint4* dst = (uint4*)&T[(size_t)(nd0 + ndr) * 1024 + h0 + hc0];
  dst[0] = o.qv[0]; dst[1] = o.qv[1];
}

// -------- sege+mask transpose: SE4[b][i][j] packed 2xbf16; MK[b][i][j] bf16 BIG*mask ---
__global__ __launch_bounds__(256)
void setrans_kernel(const float* __restrict__ sege, const float* __restrict__ amask,
                    u16* __restrict__ SE4, u16* __restrict__ MK) {
  const int i = blockIdx.x;
  const int j = blockIdx.y * 256 + threadIdx.x;
  const float* sp = &sege[((size_t)i * 512 + j) * 16];
  const float* mp = &amask[((size_t)i * 512 + j) * 8];
  float se[16], mk[8];
#pragma unroll
  for (int q = 0; q < 4; ++q) {
    const float4 f = *(const float4*)(sp + q * 4);
    se[q * 4 + 0] = f.x; se[q * 4 + 1] = f.y; se[q * 4 + 2] = f.z; se[q * 4 + 3] = f.w;
  }
#pragma unroll
  for (int q = 0; q < 2; ++q) {
    const float4 f = *(const float4*)(mp + q * 4);
    mk[q * 4 + 0] = f.x; mk[q * 4 + 1] = f.y; mk[q * 4 + 2] = f.z; mk[q * 4 + 3] = f.w;
  }
#pragma unroll
  for (int b = 0; b < 8; ++b) {
    const u32 pk = (u32)f2bf(se[b * 2]) | ((u32)f2bf(se[b * 2 + 1]) << 16);
    const size_t plane = ((size_t)b * 512 + i) * 512 + j;
    *(u32*)&SE4[plane * 2] = pk;
    MK[plane] = f2bf(BIGNUM * mk[b]);
  }
}

// ---------------- e_s = (q + r_s_bias) . seg_mat[s], s in {0,1} ----------------
__global__ __launch_bounds__(256)
void seg_e_kernel(const u16* __restrict__ Qh, const float* __restrict__ rsb,
                  const float* __restrict__ segm, float* __restrict__ E) {
  const int gt = blockIdx.x * 256 + threadIdx.x;  // gt = (i*BSZ+b)*NHEAD + n
  const int i = gt >> 7, bb = (gt >> 4) & 7, n = gt & 15;
  const size_t base = (((size_t)bb * 16 + n) * 512 + i) * 64;
  float e0 = 0.f, e1 = 0.f;
#pragma unroll
  for (int u8 = 0; u8 < 8; ++u8) {
    const uint4 qv = *(const uint4*)&Qh[base + u8 * 8];
    float qf[8];
    bf8_to_f(qv, qf);
#pragma unroll
    for (int w = 0; w < 8; ++w) {
      const int d = u8 * 8 + w;
      const float q = qf[w] + rsb[n * HDIM + d];
      e0 += q * segm[n * HDIM + d];
      e1 += q * segm[HIDN + n * HDIM + d];
    }
  }
  E[(size_t)gt * 2 + 0] = e0;
  E[(size_t)gt * 2 + 1] = e1;
}

// ---------------- MFMA fused attention: software-pipelined (K/Kr prefetch ping-pong) --
// j-half-tile 32, 2 halves per loop body. No-max softmax, deferred denominator.
// XCD swizzle: id = b + 8*(n + 16*i0blk).

#define LOADK(KF, KRF, JB)                                                          \
  {                                                                                 \
    _Pragma("unroll")                                                               \
    for (int c = 0; c < 2; ++c) {                                                   \
      const u16* kp = &Kh[((size_t)bn * 512 + (JB) + 16 * c + l15) * 64 + g * 8];   \
      KF[c][0] = *(const bf16x8*)kp;                                                \
      KF[c][1] = *(const bf16x8*)(kp + 32);                                         \
    }                                                                               \
    const int ub_ = (JB) + 497 - irow0;                                             \
    _Pragma("unroll")                                                               \
    for (int c = 0; c < 3; ++c) {                                                   \
      int ur = ub_ + 16 * c + l15;                                                  \
      ur = ur < (PLEN_ - 1) ? ur : (PLEN_ - 1);                                     \
      const u16* kp = &Krh[((size_t)bn * 1024 + ur) * 64 + g * 8];                  \
      KRF[c][0] = *(const bf16x8*)kp;                                               \
      KRF[c][1] = *(const bf16x8*)(kp + 32);                                        \
    }                                                                               \
  }

#define LOADM(VF, SEV, MKV, JB)                                                     \
  {                                                                                 \
    _Pragma("unroll")                                                               \
    for (int c = 0; c < 4; ++c)                                                     \
      VF[c] = *(const bf16x8*)&Vt2[(((size_t)bn * 8 + ((JB) >> 6)) * 64 + 16 * c + l15) * 64 + ((JB) & 63) + g * 8]; \
    _Pragma("unroll")                                                               \
    for (int c = 0; c < 2; ++c)                                                     \
      _Pragma("unroll")                                                             \
      for (int r = 0; r < 4; ++r) {                                                 \
        const size_t plane = ((size_t)b * 512 + (irow0 + 4 * g + r)) * 512 + (JB) + 16 * c + l15; \
        SEV[c][r] = *(const u32*)&SE4[plane * 2];                                   \
        MKV[c][r] = MK[plane];                                                      \
      }                                                                             \
  }

#define COMPUTE(JB, KF, KRF, VF, SEV, MKV)                                          \
  {                                                                                 \
    f32x4 S[2];                                                                     \
    _Pragma("unroll")                                                               \
    for (int c = 0; c < 2; ++c) {                                                   \
      S[c] = (f32x4){0.f, 0.f, 0.f, 0.f};                                           \
      S[c] = __builtin_amdgcn_mfma_f32_16x16x32_bf16(qcf[0], KF[c][0], S[c], 0, 0, 0); \
      S[c] = __builtin_amdgcn_mfma_f32_16x16x32_bf16(qcf[1], KF[c][1], S[c], 0, 0, 0); \
    }                                                                               \
    f32x4 T[3];                                                                     \
    _Pragma("unroll")                                                               \
    for (int c = 0; c < 3; ++c) {                                                   \
      T[c] = (f32x4){0.f, 0.f, 0.f, 0.f};                                           \
      T[c] = __builtin_amdgcn_mfma_f32_16x16x32_bf16(qrf[0], KRF[c][0], T[c], 0, 0, 0); \
      T[c] = __builtin_amdgcn_mfma_f32_16x16x32_bf16(qrf[1], KRF[c][1], T[c], 0, 0, 0); \
    }                                                                               \
    float bd[2][4];                                                                 \
    _Pragma("unroll")                                                               \
    for (int r = 0; r < 4; ++r) {                                                   \
      const int ii = 4 * g + r;                                                     \
      const int pos = (l15 + 15 - ii) & 15;                                         \
      const int srcl = (lane & 48) | pos;                                           \
      float bp[3];                                                                  \
      _Pragma("unroll")                                                             \
      for (int c = 0; c < 3; ++c) bp[c] = __shfl(T[c][r], srcl, 64);                \
      const bool sel = l15 > ii;                                                    \
      _Pragma("unroll")                                                             \
      for (int c = 0; c < 2; ++c) bd[c][r] = sel ? bp[c + 1] : bp[c];               \
    }                                                                               \
    _Pragma("unroll")                                                               \
    for (int c = 0; c < 2; ++c)                                                     \
      _Pragma("unroll")                                                             \
      for (int r = 0; r < 4; ++r) {                                                 \
        const u32 sev_ = SEV[c][r];                                                 \
        const float s = S[c][r] + bd[c][r] + bflo(sev_) * e0v[r]                    \
                        + bfhi(sev_) * e1v[r] - bflo((u32)MKV[c][r]);               \
        const float p = __expf(s);                                                  \
        S[c][r] = p;                                                                \
        lrun[r] += p;                                                               \
      }                                                                             \
    _Pragma("unroll")                                                               \
    for (int c = 0; c < 2; ++c)                                                     \
      _Pragma("unroll")                                                             \
      for (int r = 0; r < 4; ++r)                                                   \
        Pw[(4 * g + r) * 40 + 16 * c + l15] = f2bf(S[c][r]);                        \
    const bf16x8 pa = *(const bf16x8*)&Pw[l15 * 40 + g * 8];                        \
    _Pragma("unroll")                                                               \
    for (int c = 0; c < 4; ++c)                                                     \
      accO[c] = __builtin_amdgcn_mfma_f32_16x16x32_bf16(pa, VF[c], accO[c], 0, 0, 0); \
  }

__global__ __launch_bounds__(256, 2)
void attn_mfma(const u16* __restrict__ Qh, const u16* __restrict__ Kh,
               const u16* __restrict__ Vt2, const u16* __restrict__ Krh,
               const float* __restrict__ E, const u16* __restrict__ SE4,
               const u16* __restrict__ MK, const float* __restrict__ rwb,
               const float* __restrict__ rrb, u16* __restrict__ AOb) {
  __shared__ u16 Pl[4][16 * 40];
  const int id = blockIdx.x;
  const int b = id & 7, n = (id >> 3) & 15;
  const int i0 = (id >> 7) * 64;
  const int bn = b * 16 + n;
  const int t = threadIdx.x, wv = t >> 6, lane = t & 63;
  const int l15 = lane & 15, g = lane >> 4;
  const int irow0 = i0 + wv * 16;
  u16* Pw = Pl[wv];
  const int bn64 = bn * 64;

  bf16x8 qcf[2], qrf[2];
#pragma unroll
  for (int h = 0; h < 2; ++h) {
    const int d0 = 32 * h + g * 8;
    const uint4 qv = *(const uint4*)&Qh[((size_t)bn * 512 + irow0 + l15) * 64 + d0];
    float qf[8]; bf8_to_f(qv, qf);
    union { u16 us[8]; bf16x8 v; } ua, ub;
#pragma unroll
    for (int w = 0; w < 8; ++w) {
      ua.us[w] = f2bf((qf[w] + rwb[n * HDIM + d0 + w]) * SCALE_F);
      ub.us[w] = f2bf((qf[w] + rrb[n * HDIM + d0 + w]) * SCALE_F);
    }
    qcf[h] = ua.v; qrf[h] = ub.v;
  }

  float e0v[4], e1v[4], lrun[4];
  f32x4 accO[4];
#pragma unroll
  for (int r = 0; r < 4; ++r) {
    const int i = irow0 + 4 * g + r;
    const float2 ee = *(const float2*)&E[((size_t)(i * BSZ + b) * NHEAD + n) * 2];
    e0v[r] = ee.x * SCALE_F; e1v[r] = ee.y * SCALE_F;
    lrun[r] = 0.f;
  }
#pragma unroll
  for (int c = 0; c < 4; ++c) accO[c] = (f32x4){0.f, 0.f, 0.f, 0.f};

  // software pipeline: K/Kr fragments prefetched one 32-j half ahead (ping-pong)
  bf16x8 KFa[2][2], KRa[3][2], KFb[2][2], KRb[3][2];
  LOADK(KFa, KRa, 0);
  for (int jb = 0; jb < I_LEN; jb += 64) {
    bf16x8 VFa[4]; u32 SEa[2][4]; u16 MKa[2][4];
    LOADM(VFa, SEa, MKa, jb);
    LOADK(KFb, KRb, jb + 32);
    COMPUTE(jb, KFa, KRa, VFa, SEa, MKa);
    bf16x8 VFb[4]; u32 SEb[2][4]; u16 MKb[2][4];
    LOADM(VFb, SEb, MKb, jb + 32);
    if (jb + 64 < I_LEN) LOADK(KFa, KRa, jb + 64);
    COMPUTE(jb + 32, KFb, KRb, VFb, SEb, MKb);
  }
  // one-time denominator reduction across the 16-lane row group
#pragma unroll
  for (int r = 0; r < 4; ++r) {
#pragma unroll
    for (int o = 1; o < 16; o <<= 1) lrun[r] += __shfl_xor(lrun[r], o);
  }
#pragma unroll
  for (int c = 0; c < 4; ++c)
#pragma unroll
    for (int r = 0; r < 4; ++r) {
      const int ii = 4 * g + r;
      AOb[(size_t)(irow0 + ii) * 8192 + bn64 + 16 * c + l15] = f2bf(accO[c][r] / lrun[r]);
    }
}

// ---------------- LayerNorm over HID=1024, one block per (i,b) row ----------------
__global__ __launch_bounds__(256)
void ln_kernel(const float* __restrict__ X, const float* __restrict__ gam,
               const float* __restrict__ bet, float* __restrict__ out) {
  const int row = blockIdx.x, t = threadIdx.x;
  const float4 x4 = *(const float4*)&X[(size_t)row * HIDN + t * 4];
  float s  = x4.x + x4.y + x4.z + x4.w;
  float sq = x4.x * x4.x + x4.y * x4.y + x4.z * x4.z + x4.w * x4.w;
#pragma unroll
  for (int o = 32; o >= 1; o >>= 1) { s += __shfl_xor(s, o); sq += __shfl_xor(sq, o); }
  __shared__ float red[8];
  const int wv = t >> 6;
  if ((t & 63) == 0) { red[wv * 2] = s; red[wv * 2 + 1] = sq; }
  __syncthreads();
  s  = red[0] + red[2] + red[4] + red[6];
  sq = red[1] + red[3] + red[5] + red[7];
  const float mu  = s * (1.f / HIDN);
  const float var = sq * (1.f / HIDN) - mu * mu;
  const float rs  = rsqrtf(var + LN_EPS);
  const float4 g4 = *(const float4*)&gam[t * 4];
  const float4 b4 = *(const float4*)&bet[t * 4];
  float4 o4;
  o4.x = (x4.x - mu) * rs * g4.x + b4.x;
  o4.y = (x4.y - mu) * rs * g4.y + b4.y;
  o4.z = (x4.z - mu) * rs * g4.z + b4.z;
  o4.w = (x4.w - mu) * rs * g4.w + b4.w;
  *(float4*)&out[(size_t)row * HIDN + t * 4] = o4;
}

extern "C" void kernel_launch(void* const* d_in, const int* in_sizes, int n_in,
                              void* d_out, int out_size, void* d_ws, size_t ws_size,
                              hipStream_t stream) {
  (void)in_sizes; (void)n_in; (void)out_size; (void)ws_size;
  const float* hidden = (const float*)d_in[0];
  const float* pos    = (const float*)d_in[1];
  const float* sege   = (const float*)d_in[2];
  const float* amask  = (const float*)d_in[3];
  const float* qw     = (const float*)d_in[4];
  const float* kw     = (const float*)d_in[5];
  const float* vw     = (const float*)d_in[6];
  const float* rw     = (const float*)d_in[7];
  const float* ow     = (const float*)d_in[8];
  const float* rwb    = (const float*)d_in[9];
  const float* rrb    = (const float*)d_in[10];
  const float* rsb    = (const float*)d_in[11];
  const float* segm   = (const float*)d_in[12];
  const float* gam    = (const float*)d_in[13];
  const float* bet    = (const float*)d_in[14];
  float* out = (float*)d_out;
  char* ws = (char*)d_ws;

  const size_t MiB = 1ull << 20;
  u16*   Wqt = (u16*)(ws);
  u16*   Wkt = (u16*)(ws + 2 * MiB);
  u16*   Wvt = (u16*)(ws + 4 * MiB);
  u16*   Wrt = (u16*)(ws + 6 * MiB);
  u16*   AOb = (u16*)(ws);
  u16*   Qh  = (u16*)(ws + 8 * MiB);
  u16*   Kh  = (u16*)(ws + 16 * MiB);
  u16*   Vt2 = (u16*)(ws + 24 * MiB);
  u16*   Krh = (u16*)(ws + 32 * MiB);
  float* X   = (float*)(ws + 32 * MiB);
  u16*   Hb  = (u16*)(ws + 48 * MiB);
  u16*   SE4 = (u16*)(ws + 48 * MiB);
  u16*   MK  = (u16*)(ws + 56 * MiB);
  float* E   = (float*)(ws + 60 * MiB);
  u16*   Wob = (u16*)(ws + 60 * MiB + 512 * 1024);

  wtrans_kernel<<<dim3(16, 16, 4), 256, 0, stream>>>(qw, kw, vw, rw, Wqt, Wkt, Wvt, Wrt);
  hcvt_kernel<<<2560, 256, 0, stream>>>(hidden, ow, Hb, Wob);
  proj_gemm<<<dim3(8, 32, 5), 256, 0, stream>>>(Hb, pos, Wqt, Wkt, Wvt, Wrt,
                                                Qh, Kh, Vt2, Krh);
  setrans_kernel<<<dim3(512, 2), 256, 0, stream>>>(sege, amask, SE4, MK);
  seg_e_kernel<<<256, 256, 0, stream>>>(Qh, rsb, segm, E);
  attn_mfma<<<1024, 256, 0, stream>>>(Qh, Kh, Vt2, Krh, E, SE4, MK, rwb, rrb, AOb);
  oproj_gemm<<<dim3(8, 64), 256, 0, stream>>>(AOb, Wob, hidden, X);
  ln_kernel<<<4096, 256, 0, stream>>>(X, gam, bet, out);
}

// Round 11
// 182.783 us; speedup vs baseline: 1.3245x; 1.3245x over previous
//
#include <hip/hip_runtime.h>
#include <hip/hip_bf16.h>

#define I_LEN 512
#define BSZ   8
#define HIDN  1024
#define NHEAD 16
#define HDIM  64
#define PLEN_ 1024
#define SCALE_F 0.125f
#define BIGNUM 1e30f
#define LN_EPS 1e-5f

typedef unsigned int   u32;
typedef unsigned short u16;
typedef __attribute__((ext_vector_type(8))) short bf16x8;
typedef __attribute__((ext_vector_type(4))) float f32x4;

__device__ __forceinline__ float bflo(u32 w) { return __uint_as_float(w << 16); }
__device__ __forceinline__ float bfhi(u32 w) { return __uint_as_float(w & 0xffff0000u); }
__device__ __forceinline__ u16 f2bf(float x) {
  u32 u = __float_as_uint(x);
  return (u16)((u + 0x7fffu + ((u >> 16) & 1u)) >> 16);
}
__device__ __forceinline__ void bf8_to_f(const uint4 v, float* f) {
  f[0] = bflo(v.x); f[1] = bfhi(v.x);
  f[2] = bflo(v.y); f[3] = bfhi(v.y);
  f[4] = bflo(v.z); f[5] = bfhi(v.z);
  f[6] = bflo(v.w); f[7] = bfhi(v.w);
}

#define GLOAD_LDS16(gp, lp) __builtin_amdgcn_global_load_lds( \
    (const __attribute__((address_space(1))) void*)(gp),      \
    (__attribute__((address_space(3))) void*)(lp), 16, 0, 0)

// ---------------- fused projection GEMM: 5-way z ----------------
// z0: Q -> head-contig Qh.  z2: V -> head-contig Vh.
// z1: K -> FRAGMENT-MAJOR Kf[bn][jt(32)][h(2)][lane(64)][8].
// z3/4: Kr halves -> FRAGMENT-MAJOR Krf[bn][t(64)][h][lane][8], tiles 16-aligned in u.
// A 128-row block covers exactly one 16-row fragment tile (i = row>>3).
__global__ __launch_bounds__(256)
void proj_gemm(const u16* __restrict__ Hb, const float* __restrict__ pos,
               const u16* __restrict__ Wqt, const u16* __restrict__ Wkt,
               const u16* __restrict__ Wvt, const u16* __restrict__ Wrt,
               u16* __restrict__ Qh, u16* __restrict__ Kf,
               u16* __restrict__ Vh, u16* __restrict__ Krf) {
  constexpr int K = 1024;
  __shared__ union {
    struct { u16 As[128 * 64]; u16 Bs[128 * 64]; } st;  // 32 KB staging
    u16 epi[4][64 * 68];                                 // per-wave head-contig epi
    u16 epiK[128 * 137];                                 // block-wide fragment epi
  } sm;
  u16* As = sm.st.As;
  u16* Bs = sm.st.Bs;
  const int z = blockIdx.z;
  const u16* Bt; u16* C;
  if (z == 0)      { Bt = Wqt; C = Qh;  }
  else if (z == 1) { Bt = Wkt; C = Kf;  }
  else if (z == 2) { Bt = Wvt; C = Vh;  }
  else if (z == 3) { Bt = Wrt; C = Krf; }
  else             { Bt = Wrt; C = Krf; }
  const float* Apos = pos + (size_t)((z == 4) ? 4096 : 0) * 1024;
  const int bm = blockIdx.y * 128, bn = blockIdx.x * 128;
  const int tid = threadIdx.x, wv = tid >> 6, lane = tid & 63;
  const int l15 = lane & 15, g = lane >> 4;
  const int wr = wv >> 1, wc = wv & 1;

  f32x4 acc[4][4];
#pragma unroll
  for (int m = 0; m < 4; ++m)
#pragma unroll
    for (int n = 0; n < 4; ++n) acc[m][n] = (f32x4){0.f, 0.f, 0.f, 0.f};

  for (int k0 = 0; k0 < K; k0 += 64) {
#pragma unroll
    for (int p = 0; p < 4; ++p) {
      const int unit = (wv * 4 + p) * 64 + lane;
      const int row = unit >> 3, up = unit & 7, c = up ^ (row & 7);
      GLOAD_LDS16(&Bt[(size_t)(bn + row) * K + k0 + c * 8], &Bs[unit * 8]);
    }
    if (z < 3) {
#pragma unroll
      for (int p = 0; p < 4; ++p) {
        const int unit = (wv * 4 + p) * 64 + lane;
        const int row = unit >> 3, up = unit & 7, c = up ^ (row & 7);
        GLOAD_LDS16(&Hb[(size_t)(bm + row) * K + k0 + c * 8], &As[unit * 8]);
      }
    } else {
#pragma unroll
      for (int p = 0; p < 4; ++p) {
        const int unit = p * 256 + tid;
        const int row = unit >> 3, up = unit & 7, c = up ^ (row & 7);
        const float* src = &Apos[(size_t)(bm + row) * K + k0 + c * 8];
        const float4 f0 = *(const float4*)src;
        const float4 f1 = *(const float4*)(src + 4);
        ushort4 h0, h1;
        h0.x = f2bf(f0.x); h0.y = f2bf(f0.y); h0.z = f2bf(f0.z); h0.w = f2bf(f0.w);
        h1.x = f2bf(f1.x); h1.y = f2bf(f1.y); h1.z = f2bf(f1.z); h1.w = f2bf(f1.w);
        *(ushort4*)&As[unit * 8] = h0;
        *(ushort4*)&As[unit * 8 + 4] = h1;
      }
    }
    __syncthreads();
#pragma unroll
    for (int h = 0; h < 2; ++h) {
      bf16x8 af[4], bfv[4];
#pragma unroll
      for (int m = 0; m < 4; ++m) {
        const int row = wr * 64 + m * 16 + l15;
        af[m] = *(const bf16x8*)&As[row * 64 + ((h * 4 + g) ^ (row & 7)) * 8];
      }
#pragma unroll
      for (int n = 0; n < 4; ++n) {
        const int col = wc * 64 + n * 16 + l15;
        bfv[n] = *(const bf16x8*)&Bs[col * 64 + ((h * 4 + g) ^ (col & 7)) * 8];
      }
#pragma unroll
      for (int m = 0; m < 4; ++m)
#pragma unroll
        for (int n = 0; n < 4; ++n)
          acc[m][n] = __builtin_amdgcn_mfma_f32_16x16x32_bf16(af[m], bfv[n], acc[m][n], 0, 0, 0);
    }
    __syncthreads();
  }
  if (z == 1 || z >= 3) {
    // fragment-major epilogue: block-wide 128x137 LDS tile, then 32 coalesced 1KB runs
    u16* E128 = sm.epiK;
#pragma unroll
    for (int m = 0; m < 4; ++m)
#pragma unroll
      for (int nf = 0; nf < 4; ++nf)
#pragma unroll
        for (int r = 0; r < 4; ++r)
          E128[(wr * 64 + m * 16 + g * 4 + r) * 137 + wc * 64 + nf * 16 + l15] =
              f2bf(acc[m][nf][r]);
    __syncthreads();
    const int tK = (z == 1) ? blockIdx.y : (blockIdx.y + ((z == 4) ? 32 : 0));
    const int TS = (z == 1) ? 32 : 64;
#pragma unroll
    for (int q = 0; q < 8; ++q) {
      const int rid = wv * 8 + q;
      const int n_loc = rid >> 4, b_ = (rid >> 1) & 7, h = rid & 1;
      union { u16 us[8]; uint4 qv; } o;
#pragma unroll
      for (int e = 0; e < 8; ++e)
        o.us[e] = E128[(l15 * 8 + b_) * 137 + n_loc * 64 + h * 32 + g * 8 + e];
      const int head = blockIdx.x * 2 + n_loc;
      const size_t base = (((size_t)(b_ * 16 + head) * TS + tK) * 2 + h) * 512 + lane * 8;
      *(uint4*)&C[base] = o.qv;
    }
  } else {
    // head-contig epilogue (Q, V)
    u16* slice = sm.epi[wv];
    __syncthreads();
#pragma unroll
    for (int m = 0; m < 4; ++m)
#pragma unroll
      for (int nf = 0; nf < 4; ++nf)
#pragma unroll
        for (int r = 0; r < 4; ++r)
          slice[(m * 16 + g * 4 + r) * 68 + nf * 16 + l15] = f2bf(acc[m][nf][r]);
#pragma unroll
    for (int it = 0; it < 8; ++it) {
      const int rl = it * 8 + (lane >> 3);
      const int cl = (lane & 7) * 8;
      const ushort4 a = *(const ushort4*)&slice[rl * 68 + cl];
      const ushort4 b2 = *(const ushort4*)&slice[rl * 68 + cl + 4];
      const int row = bm + wr * 64 + rl;
      const int col = bn + wc * 64 + cl;
      const size_t idx = ((size_t)((row & 7) * 16 + (col >> 6)) * 512 + (row >> 3)) * 64 + (col & 63);
      *(ushort4*)&C[idx] = a;
      *(ushort4*)&C[idx + 4] = b2;
    }
  }
}

// ---------------- V repack (IN-PLACE): Vh[bn][j][d] -> Vf[bn][j64][c][h][lane][8] -------
// Block (bn, slab): reads its own 8KB slab into LDS, barrier, rewrites the SAME bytes.
__global__ __launch_bounds__(256)
void vrepack_kernel(u16* __restrict__ V) {
  __shared__ u16 tile[64][72];
  const int bn = blockIdx.x, slab = blockIdx.y;
  const int t = threadIdx.x;
  const size_t base = ((size_t)bn * 8 + slab) * 4096;   // u16 offset of this 8KB slab
  {
    const int jl = t >> 2, c0 = (t & 3) * 16;
    const uint4 v0 = *(const uint4*)&V[base + jl * 64 + c0];
    const uint4 v1 = *(const uint4*)&V[base + jl * 64 + c0 + 8];
    *(uint4*)&tile[jl][c0] = v0;
    *(uint4*)&tile[jl][c0 + 8] = v1;
  }
  __syncthreads();
  const int lane = t & 63, g = lane >> 4, l15 = lane & 15;
#pragma unroll
  for (int w = 0; w < 2; ++w) {
    const int run = w * 4 + (t >> 6);       // run = c*2 + h
    const int c = run >> 1, h = run & 1;
    union { u16 us[8]; uint4 qv; } o;
#pragma unroll
    for (int e = 0; e < 8; ++e) o.us[e] = tile[h * 32 + g * 8 + e][16 * c + l15];
    *(uint4*)&V[base + run * 512 + lane * 8] = o.qv;
  }
}

// ---------------- hidden + ow f32 -> bf16 ----------------
__global__ __launch_bounds__(256)
void hcvt_kernel(const float* __restrict__ hidden, const float* __restrict__ ow,
                 u16* __restrict__ Hb, u16* __restrict__ Wob) {
  const size_t i = (size_t)blockIdx.x * 256 + threadIdx.x;
  const float* src; u16* dst; size_t off;
  if (i < 524288) { src = hidden; dst = Hb; off = i * 8; }
  else            { src = ow;     dst = Wob; off = (i - 524288) * 8; }
  const float4 a = *(const float4*)&src[off];
  const float4 b = *(const float4*)&src[off + 4];
  ushort4 o0, o1;
  o0.x = f2bf(a.x); o0.y = f2bf(a.y); o0.z = f2bf(a.z); o0.w = f2bf(a.w);
  o1.x = f2bf(b.x); o1.y = f2bf(b.y); o1.z = f2bf(b.z); o1.w = f2bf(b.w);
  *(ushort4*)&dst[off] = o0;
  *(ushort4*)&dst[off + 4] = o1;
}

// ---------------- weight transpose+cvt: W[h][nd] f32 -> T[nd][h] bf16 ----------------
__global__ __launch_bounds__(256)
void wtrans_kernel(const float* __restrict__ W0, const float* __restrict__ W1,
                   const float* __restrict__ W2, const float* __restrict__ W3,
                   u16* __restrict__ T0, u16* __restrict__ T1,
                   u16* __restrict__ T2, u16* __restrict__ T3) {
  __shared__ u16 tile[64][72];
  const int z = blockIdx.z;
  const float* W = (z == 0) ? W0 : ((z == 1) ? W1 : ((z == 2) ? W2 : W3));
  u16* T = (z == 0) ? T0 : ((z == 1) ? T1 : ((z == 2) ? T2 : T3));
  const int h0 = blockIdx.y * 64, nd0 = blockIdx.x * 64;
  const int t = threadIdx.x;
  {
    const int hr = t >> 2, c0 = (t & 3) * 16;
#pragma unroll
    for (int q = 0; q < 4; ++q) {
      const float4 f = *(const float4*)&W[(size_t)(h0 + hr) * 1024 + nd0 + c0 + q * 4];
      tile[hr][c0 + q * 4 + 0] = f2bf(f.x);
      tile[hr][c0 + q * 4 + 1] = f2bf(f.y);
      tile[hr][c0 + q * 4 + 2] = f2bf(f.z);
      tile[hr][c0 + q * 4 + 3] = f2bf(f.w);
    }
  }
  __syncthreads();
  const int ndr = t >> 2, hc0 = (t & 3) * 16;
  union { u16 us[16]; uint4 qv[2]; } o;
#pragma unroll
  for (int e = 0; e < 16; ++e) o.us[e] = tile[hc0 + e][ndr];
  uint4* dst = (uint4*)&T[(size_t)(nd0 + ndr) * 1024 + h0 + hc0];
  dst[0] = o.qv[0]; dst[1] = o.qv[1];
}

// -------- sege+mask transpose: SE4[b][i][j] packed 2xbf16; MK[b][i][j] bf16 BIG*mask ---
__global__ __launch_bounds__(256)
void setrans_kernel(const float* __restrict__ sege, const float* __restrict__ amask,
                    u16* __restrict__ SE4, u16* __restrict__ MK) {
  const int i = blockIdx.x;
  const int j = blockIdx.y * 256 + threadIdx.x;
  const float* sp = &sege[((size_t)i * 512 + j) * 16];
  const float* mp = &amask[((size_t)i * 512 + j) * 8];
  float se[16], mk[8];
#pragma unroll
  for (int q = 0; q < 4; ++q) {
    const float4 f = *(const float4*)(sp + q * 4);
    se[q * 4 + 0] = f.x; se[q * 4 + 1] = f.y; se[q * 4 + 2] = f.z; se[q * 4 + 3] = f.w;
  }
#pragma unroll
  for (int q = 0; q < 2; ++q) {
    const float4 f = *(const float4*)(mp + q * 4);
    mk[q * 4 + 0] = f.x; mk[q * 4 + 1] = f.y; mk[q * 4 + 2] = f.z; mk[q * 4 + 3] = f.w;
  }
#pragma unroll
  for (int b = 0; b < 8; ++b) {
    const u32 pk = (u32)f2bf(se[b * 2]) | ((u32)f2bf(se[b * 2 + 1]) << 16);
    const size_t plane = ((size_t)b * 512 + i) * 512 + j;
    *(u32*)&SE4[plane * 2] = pk;
    MK[plane] = f2bf(BIGNUM * mk[b]);
  }
}

// ---------------- e_s = (q + r_s_bias) . seg_mat[s], s in {0,1} ----------------
__global__ __launch_bounds__(256)
void seg_e_kernel(const u16* __restrict__ Qh, const float* __restrict__ rsb,
                  const float* __restrict__ segm, float* __restrict__ E) {
  const int gt = blockIdx.x * 256 + threadIdx.x;  // gt = (i*BSZ+b)*NHEAD + n
  const int i = gt >> 7, bb = (gt >> 4) & 7, n = gt & 15;
  const size_t base = (((size_t)bb * 16 + n) * 512 + i) * 64;
  float e0 = 0.f, e1 = 0.f;
#pragma unroll
  for (int u8 = 0; u8 < 8; ++u8) {
    const uint4 qv = *(const uint4*)&Qh[base + u8 * 8];
    float qf[8];
    bf8_to_f(qv, qf);
#pragma unroll
    for (int w = 0; w < 8; ++w) {
      const int d = u8 * 8 + w;
      const float q = qf[w] + rsb[n * HDIM + d];
      e0 += q * segm[n * HDIM + d];
      e1 += q * segm[HIDN + n * HDIM + d];
    }
  }
  E[(size_t)gt * 2 + 0] = e0;
  E[(size_t)gt * 2 + 1] = e1;
}

// ---------------- MFMA fused attention: fragment-major coalesced operands -------------
// j-tile 64. All K/Kr/V loads are contiguous 1KB bursts (fragment-major layouts).
// Kr tiles 16-aligned: sel = l15>=ii, pos = (l15-ii)&15 — no row clamp needed.
// No-max softmax (scores O(10); masked -> exp(-1e30)=0), deferred denominator.
// XCD swizzle: id = b + 8*(n + 16*i0blk).
__global__ __launch_bounds__(256)
void attn_mfma(const u16* __restrict__ Qh, const u16* __restrict__ Kf,
               const u16* __restrict__ Vf, const u16* __restrict__ Krf,
               const float* __restrict__ E, const u16* __restrict__ SE4,
               const u16* __restrict__ MK, const float* __restrict__ rwb,
               const float* __restrict__ rrb, u16* __restrict__ AOb) {
  __shared__ u16 Pl[4][16 * 64];   // 8 KB: per-wave P tile, XOR-swizzled (0 conflicts)
  const int id = blockIdx.x;
  const int b = id & 7, n = (id >> 3) & 15;
  const int i0 = (id >> 7) * 64;
  const int bn = b * 16 + n;
  const int t = threadIdx.x, wv = t >> 6, lane = t & 63;
  const int l15 = lane & 15, g = lane >> 4;
  const int irow0 = i0 + wv * 16;
  u16* Pw = Pl[wv];
  const int bn64 = bn * 64;

  // Q fragments with bias, pre-scaled by SCALE (2^-3 exact in bf16)
  bf16x8 qcf[2], qrf[2];
#pragma unroll
  for (int h = 0; h < 2; ++h) {
    const int d0 = 32 * h + g * 8;
    const uint4 qv = *(const uint4*)&Qh[((size_t)bn * 512 + irow0 + l15) * 64 + d0];
    float qf[8]; bf8_to_f(qv, qf);
    union { u16 us[8]; bf16x8 v; } ua, ub;
#pragma unroll
    for (int w = 0; w < 8; ++w) {
      ua.us[w] = f2bf((qf[w] + rwb[n * HDIM + d0 + w]) * SCALE_F);
      ub.us[w] = f2bf((qf[w] + rrb[n * HDIM + d0 + w]) * SCALE_F);
    }
    qcf[h] = ua.v; qrf[h] = ub.v;
  }

  float e0v[4], e1v[4], lrun[4];
  f32x4 accO[4];
#pragma unroll
  for (int r = 0; r < 4; ++r) {
    const int i = irow0 + 4 * g + r;
    const float2 ee = *(const float2*)&E[((size_t)(i * BSZ + b) * NHEAD + n) * 2];
    e0v[r] = ee.x * SCALE_F; e1v[r] = ee.y * SCALE_F;
    lrun[r] = 0.f;
  }
#pragma unroll
  for (int c = 0; c < 4; ++c) accO[c] = (f32x4){0.f, 0.f, 0.f, 0.f};

  for (int jb = 0; jb < I_LEN; jb += 64) {
    // prefetch SE/MK and V fragments (coalesced)
    u32 sev[4][4]; u16 mkv[4][4];
#pragma unroll
    for (int c = 0; c < 4; ++c)
#pragma unroll
      for (int r = 0; r < 4; ++r) {
        const size_t plane = ((size_t)b * 512 + (irow0 + 4 * g + r)) * 512 + jb + 16 * c + l15;
        sev[c][r] = *(const u32*)&SE4[plane * 2];
        mkv[c][r] = MK[plane];
      }
    bf16x8 vf[4][2];
#pragma unroll
    for (int c = 0; c < 4; ++c) {
      const u16* vp = &Vf[((((size_t)bn * 8 + (jb >> 6)) * 4 + c) * 2) * 512 + lane * 8];
      vf[c][0] = *(const bf16x8*)vp;
      vf[c][1] = *(const bf16x8*)(vp + 512);
    }
    // ac scores: fragment-major K (contiguous 1KB per load)
    f32x4 S[4];
#pragma unroll
    for (int c = 0; c < 4; ++c) S[c] = (f32x4){0.f, 0.f, 0.f, 0.f};
#pragma unroll
    for (int c = 0; c < 4; ++c) {
      const u16* kp = &Kf[(((size_t)bn * 32 + (jb >> 4) + c) * 2) * 512 + lane * 8];
      S[c] = __builtin_amdgcn_mfma_f32_16x16x32_bf16(qcf[0], *(const bf16x8*)kp, S[c], 0, 0, 0);
      S[c] = __builtin_amdgcn_mfma_f32_16x16x32_bf16(qcf[1], *(const bf16x8*)(kp + 512), S[c], 0, 0, 0);
    }
    // bd window: 5 aligned Kr fragment tiles (contiguous loads, no clamp)
    const int tb = (jb + 496 - irow0) >> 4;   // 16-aligned; tb+4 <= 63
    f32x4 T[5];
#pragma unroll
    for (int c = 0; c < 5; ++c) T[c] = (f32x4){0.f, 0.f, 0.f, 0.f};
#pragma unroll
    for (int c = 0; c < 5; ++c) {
      const u16* kp = &Krf[(((size_t)bn * 64 + tb + c) * 2) * 512 + lane * 8];
      T[c] = __builtin_amdgcn_mfma_f32_16x16x32_bf16(qrf[0], *(const bf16x8*)kp, T[c], 0, 0, 0);
      T[c] = __builtin_amdgcn_mfma_f32_16x16x32_bf16(qrf[1], *(const bf16x8*)(kp + 512), T[c], 0, 0, 0);
    }
    // rel-shift gather via bpermute (aligned-tile version)
    float bd[4][4];
#pragma unroll
    for (int r = 0; r < 4; ++r) {
      const int ii = 4 * g + r;
      const int pos = (lane & 48) | ((l15 - ii) & 15);
      float bp[5];
#pragma unroll
      for (int c = 0; c < 5; ++c) bp[c] = __shfl(T[c][r], pos, 64);
      const bool sel = l15 >= ii;
#pragma unroll
      for (int c = 0; c < 4; ++c) bd[c][r] = sel ? bp[c + 1] : bp[c];
    }
    // assemble + direct exp (no max), accumulate denominator in-lane
#pragma unroll
    for (int c = 0; c < 4; ++c)
#pragma unroll
      for (int r = 0; r < 4; ++r) {
        const u32 sev_ = sev[c][r];
        const float s = S[c][r] + bd[c][r] + bflo(sev_) * e0v[r] + bfhi(sev_) * e1v[r]
                        - bflo((u32)mkv[c][r]);
        const float p = __expf(s);
        S[c][r] = p;
        lrun[r] += p;
      }
    // P -> LDS (XOR swizzle) -> A-fragments
#pragma unroll
    for (int c = 0; c < 4; ++c)
#pragma unroll
      for (int r = 0; r < 4; ++r) {
        const int ii = 4 * g + r;
        Pw[ii * 64 + ((16 * c + l15) ^ ((ii & 7) << 3))] = f2bf(S[c][r]);
      }
    const bf16x8 pa0 = *(const bf16x8*)&Pw[l15 * 64 + ((g * 8) ^ ((l15 & 7) << 3))];
    const bf16x8 pa1 = *(const bf16x8*)&Pw[l15 * 64 + ((32 + g * 8) ^ ((l15 & 7) << 3))];
    // PV
#pragma unroll
    for (int c = 0; c < 4; ++c) {
      accO[c] = __builtin_amdgcn_mfma_f32_16x16x32_bf16(pa0, vf[c][0], accO[c], 0, 0, 0);
      accO[c] = __builtin_amdgcn_mfma_f32_16x16x32_bf16(pa1, vf[c][1], accO[c], 0, 0, 0);
    }
  }
  // one-time denominator reduction across the 16-lane row group
#pragma unroll
  for (int r = 0; r < 4; ++r) {
#pragma unroll
    for (int o = 1; o < 16; o <<= 1) lrun[r] += __shfl_xor(lrun[r], o);
  }
#pragma unroll
  for (int c = 0; c < 4; ++c)
#pragma unroll
    for (int r = 0; r < 4; ++r) {
      const int ii = 4 * g + r;
      AOb[(size_t)(irow0 + ii) * 8192 + bn64 + 16 * c + l15] = f2bf(accO[c][r] / lrun[r]);
    }
}

// ---------------- O-projection GEMM: 64x128 tile, A bf16, B=Wob bf16, C f32 + residual --
__global__ __launch_bounds__(256)
void oproj_gemm(const u16* __restrict__ A, const u16* __restrict__ Wob,
                const float* __restrict__ Res, float* __restrict__ C) {
  constexpr int K = 1024;
  __shared__ u16 As[64 * 64];
  __shared__ u16 Bs[128 * 64];
  const int bm = blockIdx.y * 64, bn = blockIdx.x * 128;
  const int tid = threadIdx.x, wv = tid >> 6, lane = tid & 63;
  const int l15 = lane & 15, g = lane >> 4;
  const int wr = wv >> 1, wc = wv & 1;

  f32x4 acc[2][4];
#pragma unroll
  for (int m = 0; m < 2; ++m)
#pragma unroll
    for (int n = 0; n < 4; ++n) acc[m][n] = (f32x4){0.f, 0.f, 0.f, 0.f};

  for (int k0 = 0; k0 < K; k0 += 64) {
#pragma unroll
    for (int p = 0; p < 2; ++p) {
      const int unit = (wv * 2 + p) * 64 + lane;
      const int row = unit >> 3, up = unit & 7, c = up ^ (row & 7);
      GLOAD_LDS16(&A[(size_t)(bm + row) * K + k0 + c * 8], &As[unit * 8]);
    }
#pragma unroll
    for (int p = 0; p < 4; ++p) {
      const int unit = (wv * 4 + p) * 64 + lane;
      const int row = unit >> 3, up = unit & 7, c = up ^ (row & 7);
      GLOAD_LDS16(&Wob[(size_t)(bn + row) * K + k0 + c * 8], &Bs[unit * 8]);
    }
    __syncthreads();
#pragma unroll
    for (int h = 0; h < 2; ++h) {
      bf16x8 af[2], bfv[4];
#pragma unroll
      for (int m = 0; m < 2; ++m) {
        const int row = wr * 32 + m * 16 + l15;
        af[m] = *(const bf16x8*)&As[row * 64 + ((h * 4 + g) ^ (row & 7)) * 8];
      }
#pragma unroll
      for (int n = 0; n < 4; ++n) {
        const int col = wc * 64 + n * 16 + l15;
        bfv[n] = *(const bf16x8*)&Bs[col * 64 + ((h * 4 + g) ^ (col & 7)) * 8];
      }
#pragma unroll
      for (int m = 0; m < 2; ++m)
#pragma unroll
        for (int n = 0; n < 4; ++n)
          acc[m][n] = __builtin_amdgcn_mfma_f32_16x16x32_bf16(af[m], bfv[n], acc[m][n], 0, 0, 0);
    }
    __syncthreads();
  }
#pragma unroll
  for (int m = 0; m < 2; ++m) {
    const int row0 = bm + wr * 32 + m * 16 + g * 4;
#pragma unroll
    for (int nf = 0; nf < 4; ++nf) {
      const int col = bn + wc * 64 + nf * 16 + l15;
#pragma unroll
      for (int r = 0; r < 4; ++r) {
        const int row = row0 + r;
        C[(size_t)row * 1024 + col] = acc[m][nf][r] + Res[(size_t)row * 1024 + col];
      }
    }
  }
}

// ---------------- LayerNorm over HID=1024, one block per (i,b) row ----------------
__global__ __launch_bounds__(256)
void ln_kernel(const float* __restrict__ X, const float* __restrict__ gam,
               const float* __restrict__ bet, float* __restrict__ out) {
  const int row = blockIdx.x, t = threadIdx.x;
  const float4 x4 = *(const float4*)&X[(size_t)row * HIDN + t * 4];
  float s  = x4.x + x4.y + x4.z + x4.w;
  float sq = x4.x * x4.x + x4.y * x4.y + x4.z * x4.z + x4.w * x4.w;
#pragma unroll
  for (int o = 32; o >= 1; o >>= 1) { s += __shfl_xor(s, o); sq += __shfl_xor(sq, o); }
  __shared__ float red[8];
  const int wv = t >> 6;
  if ((t & 63) == 0) { red[wv * 2] = s; red[wv * 2 + 1] = sq; }
  __syncthreads();
  s  = red[0] + red[2] + red[4] + red[6];
  sq = red[1] + red[3] + red[5] + red[7];
  const float mu  = s * (1.f / HIDN);
  const float var = sq * (1.f / HIDN) - mu * mu;
  const float rs  = rsqrtf(var + LN_EPS);
  const float4 g4 = *(const float4*)&gam[t * 4];
  const float4 b4 = *(const float4*)&bet[t * 4];
  float4 o4;
  o4.x = (x4.x - mu) * rs * g4.x + b4.x;
  o4.y = (x4.y - mu) * rs * g4.y + b4.y;
  o4.z = (x4.z - mu) * rs * g4.z + b4.z;
  o4.w = (x4.w - mu) * rs * g4.w + b4.w;
  *(float4*)&out[(size_t)row * HIDN + t * 4] = o4;
}

extern "C" void kernel_launch(void* const* d_in, const int* in_sizes, int n_in,
                              void* d_out, int out_size, void* d_ws, size_t ws_size,
                              hipStream_t stream) {
  (void)in_sizes; (void)n_in; (void)out_size; (void)ws_size;
  const float* hidden = (const float*)d_in[0];
  const float* pos    = (const float*)d_in[1];
  const float* sege   = (const float*)d_in[2];
  const float* amask  = (const float*)d_in[3];
  const float* qw     = (const float*)d_in[4];
  const float* kw     = (const float*)d_in[5];
  const float* vw     = (const float*)d_in[6];
  const float* rw     = (const float*)d_in[7];
  const float* ow     = (const float*)d_in[8];
  const float* rwb    = (const float*)d_in[9];
  const float* rrb    = (const float*)d_in[10];
  const float* rsb    = (const float*)d_in[11];
  const float* segm   = (const float*)d_in[12];
  const float* gam    = (const float*)d_in[13];
  const float* bet    = (const float*)d_in[14];
  float* out = (float*)d_out;
  char* ws = (char*)d_ws;

  const size_t MiB = 1ull << 20;
  // layout (62.5 MiB, proven):
  // [0,8):    Wqt..Wrt (weights) -> AOb after proj
  // [8,16):   Qh
  // [16,24):  Kf  (fragment-major, written by proj z==1)
  // [24,32):  Vh -> Vf IN PLACE (vrepack)
  // [32,48):  Krf (fragment-major, proj z==3/4) -> X f32 after attn
  // [48,56):  Hb (dead after proj) -> SE4
  // [56,60):  MK
  // [60,60.5): E
  // [60.5,62.5): Wob
  u16*   Wqt = (u16*)(ws);
  u16*   Wkt = (u16*)(ws + 2 * MiB);
  u16*   Wvt = (u16*)(ws + 4 * MiB);
  u16*   Wrt = (u16*)(ws + 6 * MiB);
  u16*   AOb = (u16*)(ws);
  u16*   Qh  = (u16*)(ws + 8 * MiB);
  u16*   Kf  = (u16*)(ws + 16 * MiB);
  u16*   Vf  = (u16*)(ws + 24 * MiB);
  u16*   Krf = (u16*)(ws + 32 * MiB);
  float* X   = (float*)(ws + 32 * MiB);
  u16*   Hb  = (u16*)(ws + 48 * MiB);
  u16*   SE4 = (u16*)(ws + 48 * MiB);
  u16*   MK  = (u16*)(ws + 56 * MiB);
  float* E   = (float*)(ws + 60 * MiB);
  u16*   Wob = (u16*)(ws + 60 * MiB + 512 * 1024);

  wtrans_kernel<<<dim3(16, 16, 4), 256, 0, stream>>>(qw, kw, vw, rw, Wqt, Wkt, Wvt, Wrt);
  hcvt_kernel<<<2560, 256, 0, stream>>>(hidden, ow, Hb, Wob);
  proj_gemm<<<dim3(8, 32, 5), 256, 0, stream>>>(Hb, pos, Wqt, Wkt, Wvt, Wrt,
                                                Qh, Kf, Vf, Krf);
  vrepack_kernel<<<dim3(128, 8), 256, 0, stream>>>(Vf);
  setrans_kernel<<<dim3(512, 2), 256, 0, stream>>>(sege, amask, SE4, MK);
  seg_e_kernel<<<256, 256, 0, stream>>>(Qh, rsb, segm, E);
  attn_mfma<<<1024, 256, 0, stream>>>(Qh, Kf, Vf, Krf, E, SE4, MK, rwb, rrb, AOb);
  oproj_gemm<<<dim3(8, 64), 256, 0, stream>>>(AOb, Wob, hidden, X);
  ln_kernel<<<4096, 256, 0, stream>>>(X, gam, bet, out);
}

// Round 12
// 168.744 us; speedup vs baseline: 1.4347x; 1.0832x over previous
//
#include <hip/hip_runtime.h>
#include <hip/hip_bf16.h>

#define I_LEN 512
#define BSZ   8
#define HIDN  1024
#define NHEAD 16
#define HDIM  64
#define PLEN_ 1024
#define SCALE_F 0.125f
#define BIGNUM 1e30f
#define LN_EPS 1e-5f

typedef unsigned int   u32;
typedef unsigned short u16;
typedef __attribute__((ext_vector_type(8))) short bf16x8;
typedef __attribute__((ext_vector_type(4))) float f32x4;

__device__ __forceinline__ float bflo(u32 w) { return __uint_as_float(w << 16); }
__device__ __forceinline__ float bfhi(u32 w) { return __uint_as_float(w & 0xffff0000u); }
__device__ __forceinline__ u16 f2bf(float x) {
  u32 u = __float_as_uint(x);
  return (u16)((u + 0x7fffu + ((u >> 16) & 1u)) >> 16);
}
__device__ __forceinline__ void bf8_to_f(const uint4 v, float* f) {
  f[0] = bflo(v.x); f[1] = bfhi(v.x);
  f[2] = bflo(v.y); f[3] = bfhi(v.y);
  f[4] = bflo(v.z); f[5] = bfhi(v.z);
  f[6] = bflo(v.w); f[7] = bfhi(v.w);
}

#define GLOAD_LDS16(gp, lp) __builtin_amdgcn_global_load_lds( \
    (const __attribute__((address_space(1))) void*)(gp),      \
    (__attribute__((address_space(3))) void*)(lp), 16, 0, 0)

// ---------------- fused projection GEMM: 5-way z, XCD-grouped 1-D grid ----------------
// Grid 1280: id = (grp&7) + 8*(x + 8*(grp>>3)), grp = y + 32*z.
// The 8 x-blocks of one (y,z) group are id-congruent mod 8 -> same XCD, consecutive
// slots -> shared A-tile is an L2 hit for 7 of 8 blocks.
// z0: Q -> head-contig Qh.  z2: V -> head-contig Vh (fragment repack later in-place).
// z1: K -> FRAGMENT-MAJOR Kf[bn][jt(32)][h(2)][lane(64)][8].
// z3/4: Kr halves -> FRAGMENT-MAJOR Krf[bn][t(64)][h][lane][8], 16-aligned tiles.
__global__ __launch_bounds__(256)
void proj_gemm(const u16* __restrict__ Hb, const float* __restrict__ pos,
               const u16* __restrict__ Wqt, const u16* __restrict__ Wkt,
               const u16* __restrict__ Wvt, const u16* __restrict__ Wrt,
               u16* __restrict__ Qh, u16* __restrict__ Kf,
               u16* __restrict__ Vh, u16* __restrict__ Krf) {
  constexpr int K = 1024;
  __shared__ union {
    struct { u16 As[128 * 64]; u16 Bs[128 * 64]; } st;  // 32 KB staging
    u16 epi[4][64 * 68];                                 // per-wave head-contig epi
    u16 epiK[128 * 137];                                 // block-wide fragment epi
  } sm;
  u16* As = sm.st.As;
  u16* Bs = sm.st.Bs;
  // XCD-grouped decode
  const int id = blockIdx.x;
  const int low = id & 7;
  const int rest = id >> 3;
  const int bx = rest & 7;
  const int grp = low + 8 * (rest >> 3);   // 0..159
  const int by = grp & 31;
  const int z = grp >> 5;
  const u16* Bt; u16* C;
  if (z == 0)      { Bt = Wqt; C = Qh;  }
  else if (z == 1) { Bt = Wkt; C = Kf;  }
  else if (z == 2) { Bt = Wvt; C = Vh;  }
  else if (z == 3) { Bt = Wrt; C = Krf; }
  else             { Bt = Wrt; C = Krf; }
  const float* Apos = pos + (size_t)((z == 4) ? 4096 : 0) * 1024;
  const int bm = by * 128, bn = bx * 128;
  const int tid = threadIdx.x, wv = tid >> 6, lane = tid & 63;
  const int l15 = lane & 15, g = lane >> 4;
  const int wr = wv >> 1, wc = wv & 1;

  f32x4 acc[4][4];
#pragma unroll
  for (int m = 0; m < 4; ++m)
#pragma unroll
    for (int n = 0; n < 4; ++n) acc[m][n] = (f32x4){0.f, 0.f, 0.f, 0.f};

  for (int k0 = 0; k0 < K; k0 += 64) {
#pragma unroll
    for (int p = 0; p < 4; ++p) {
      const int unit = (wv * 4 + p) * 64 + lane;
      const int row = unit >> 3, up = unit & 7, c = up ^ (row & 7);
      GLOAD_LDS16(&Bt[(size_t)(bn + row) * K + k0 + c * 8], &Bs[unit * 8]);
    }
    if (z < 3) {
#pragma unroll
      for (int p = 0; p < 4; ++p) {
        const int unit = (wv * 4 + p) * 64 + lane;
        const int row = unit >> 3, up = unit & 7, c = up ^ (row & 7);
        GLOAD_LDS16(&Hb[(size_t)(bm + row) * K + k0 + c * 8], &As[unit * 8]);
      }
    } else {
#pragma unroll
      for (int p = 0; p < 4; ++p) {
        const int unit = p * 256 + tid;
        const int row = unit >> 3, up = unit & 7, c = up ^ (row & 7);
        const float* src = &Apos[(size_t)(bm + row) * K + k0 + c * 8];
        const float4 f0 = *(const float4*)src;
        const float4 f1 = *(const float4*)(src + 4);
        ushort4 h0, h1;
        h0.x = f2bf(f0.x); h0.y = f2bf(f0.y); h0.z = f2bf(f0.z); h0.w = f2bf(f0.w);
        h1.x = f2bf(f1.x); h1.y = f2bf(f1.y); h1.z = f2bf(f1.z); h1.w = f2bf(f1.w);
        *(ushort4*)&As[unit * 8] = h0;
        *(ushort4*)&As[unit * 8 + 4] = h1;
      }
    }
    __syncthreads();
#pragma unroll
    for (int h = 0; h < 2; ++h) {
      bf16x8 af[4], bfv[4];
#pragma unroll
      for (int m = 0; m < 4; ++m) {
        const int row = wr * 64 + m * 16 + l15;
        af[m] = *(const bf16x8*)&As[row * 64 + ((h * 4 + g) ^ (row & 7)) * 8];
      }
#pragma unroll
      for (int n = 0; n < 4; ++n) {
        const int col = wc * 64 + n * 16 + l15;
        bfv[n] = *(const bf16x8*)&Bs[col * 64 + ((h * 4 + g) ^ (col & 7)) * 8];
      }
#pragma unroll
      for (int m = 0; m < 4; ++m)
#pragma unroll
        for (int n = 0; n < 4; ++n)
          acc[m][n] = __builtin_amdgcn_mfma_f32_16x16x32_bf16(af[m], bfv[n], acc[m][n], 0, 0, 0);
    }
    __syncthreads();
  }
  if (z == 1 || z >= 3) {
    // fragment-major epilogue: block-wide 128x137 LDS tile, then 32 coalesced 1KB runs
    u16* E128 = sm.epiK;
#pragma unroll
    for (int m = 0; m < 4; ++m)
#pragma unroll
      for (int nf = 0; nf < 4; ++nf)
#pragma unroll
        for (int r = 0; r < 4; ++r)
          E128[(wr * 64 + m * 16 + g * 4 + r) * 137 + wc * 64 + nf * 16 + l15] =
              f2bf(acc[m][nf][r]);
    __syncthreads();
    const int tK = (z == 1) ? by : (by + ((z == 4) ? 32 : 0));
    const int TS = (z == 1) ? 32 : 64;
#pragma unroll
    for (int q = 0; q < 8; ++q) {
      const int rid = wv * 8 + q;
      const int n_loc = rid >> 4, b_ = (rid >> 1) & 7, h = rid & 1;
      union { u16 us[8]; uint4 qv; } o;
#pragma unroll
      for (int e = 0; e < 8; ++e)
        o.us[e] = E128[(l15 * 8 + b_) * 137 + n_loc * 64 + h * 32 + g * 8 + e];
      const int head = bx * 2 + n_loc;
      const size_t base = (((size_t)(b_ * 16 + head) * TS + tK) * 2 + h) * 512 + lane * 8;
      *(uint4*)&C[base] = o.qv;
    }
  } else {
    // head-contig epilogue (Q, V)
    u16* slice = sm.epi[wv];
    __syncthreads();
#pragma unroll
    for (int m = 0; m < 4; ++m)
#pragma unroll
      for (int nf = 0; nf < 4; ++nf)
#pragma unroll
        for (int r = 0; r < 4; ++r)
          slice[(m * 16 + g * 4 + r) * 68 + nf * 16 + l15] = f2bf(acc[m][nf][r]);
#pragma unroll
    for (int it = 0; it < 8; ++it) {
      const int rl = it * 8 + (lane >> 3);
      const int cl = (lane & 7) * 8;
      const ushort4 a = *(const ushort4*)&slice[rl * 68 + cl];
      const ushort4 b2 = *(const ushort4*)&slice[rl * 68 + cl + 4];
      const int row = bm + wr * 64 + rl;
      const int col = bn + wc * 64 + cl;
      const size_t idx = ((size_t)((row & 7) * 16 + (col >> 6)) * 512 + (row >> 3)) * 64 + (col & 63);
      *(ushort4*)&C[idx] = a;
      *(ushort4*)&C[idx + 4] = b2;
    }
  }
}

// ---------------- V repack (IN-PLACE): Vh[bn][j][d] -> Vf[bn][j64][c][h][lane][8] -------
__global__ __launch_bounds__(256)
void vrepack_kernel(u16* __restrict__ V) {
  __shared__ u16 tile[64][72];
  const int bn = blockIdx.x, slab = blockIdx.y;
  const int t = threadIdx.x;
  const size_t base = ((size_t)bn * 8 + slab) * 4096;
  {
    const int jl = t >> 2, c0 = (t & 3) * 16;
    const uint4 v0 = *(const uint4*)&V[base + jl * 64 + c0];
    const uint4 v1 = *(const uint4*)&V[base + jl * 64 + c0 + 8];
    *(uint4*)&tile[jl][c0] = v0;
    *(uint4*)&tile[jl][c0 + 8] = v1;
  }
  __syncthreads();
  const int lane = t & 63, g = lane >> 4, l15 = lane & 15;
#pragma unroll
  for (int w = 0; w < 2; ++w) {
    const int run = w * 4 + (t >> 6);
    const int c = run >> 1, h = run & 1;
    union { u16 us[8]; uint4 qv; } o;
#pragma unroll
    for (int e = 0; e < 8; ++e) o.us[e] = tile[h * 32 + g * 8 + e][16 * c + l15];
    *(uint4*)&V[base + run * 512 + lane * 8] = o.qv;
  }
}

// ---------------- hidden + ow f32 -> bf16 ----------------
__global__ __launch_bounds__(256)
void hcvt_kernel(const float* __restrict__ hidden, const float* __restrict__ ow,
                 u16* __restrict__ Hb, u16* __restrict__ Wob) {
  const size_t i = (size_t)blockIdx.x * 256 + threadIdx.x;
  const float* src; u16* dst; size_t off;
  if (i < 524288) { src = hidden; dst = Hb; off = i * 8; }
  else            { src = ow;     dst = Wob; off = (i - 524288) * 8; }
  const float4 a = *(const float4*)&src[off];
  const float4 b = *(const float4*)&src[off + 4];
  ushort4 o0, o1;
  o0.x = f2bf(a.x); o0.y = f2bf(a.y); o0.z = f2bf(a.z); o0.w = f2bf(a.w);
  o1.x = f2bf(b.x); o1.y = f2bf(b.y); o1.z = f2bf(b.z); o1.w = f2bf(b.w);
  *(ushort4*)&dst[off] = o0;
  *(ushort4*)&dst[off + 4] = o1;
}

// ---------------- weight transpose+cvt: W[h][nd] f32 -> T[nd][h] bf16 ----------------
__global__ __launch_bounds__(256)
void wtrans_kernel(const float* __restrict__ W0, const float* __restrict__ W1,
                   const float* __restrict__ W2, const float* __restrict__ W3,
                   u16* __restrict__ T0, u16* __restrict__ T1,
                   u16* __restrict__ T2, u16* __restrict__ T3) {
  __shared__ u16 tile[64][72];
  const int z = blockIdx.z;
  const float* W = (z == 0) ? W0 : ((z == 1) ? W1 : ((z == 2) ? W2 : W3));
  u16* T = (z == 0) ? T0 : ((z == 1) ? T1 : ((z == 2) ? T2 : T3));
  const int h0 = blockIdx.y * 64, nd0 = blockIdx.x * 64;
  const int t = threadIdx.x;
  {
    const int hr = t >> 2, c0 = (t & 3) * 16;
#pragma unroll
    for (int q = 0; q < 4; ++q) {
      const float4 f = *(const float4*)&W[(size_t)(h0 + hr) * 1024 + nd0 + c0 + q * 4];
      tile[hr][c0 + q * 4 + 0] = f2bf(f.x);
      tile[hr][c0 + q * 4 + 1] = f2bf(f.y);
      tile[hr][c0 + q * 4 + 2] = f2bf(f.z);
      tile[hr][c0 + q * 4 + 3] = f2bf(f.w);
    }
  }
  __syncthreads();
  const int ndr = t >> 2, hc0 = (t & 3) * 16;
  union { u16 us[16]; uint4 qv[2]; } o;
#pragma unroll
  for (int e = 0; e < 16; ++e) o.us[e] = tile[hc0 + e][ndr];
  uint4* dst = (uint4*)&T[(size_t)(nd0 + ndr) * 1024 + h0 + hc0];
  dst[0] = o.qv[0]; dst[1] = o.qv[1];
}

// -------- sege+mask transpose: SE4[b][i][j] packed 2xbf16; MK[b][i][j] bf16 BIG*mask ---
__global__ __launch_bounds__(256)
void setrans_kernel(const float* __restrict__ sege, const float* __restrict__ amask,
                    u16* __restrict__ SE4, u16* __restrict__ MK) {
  const int i = blockIdx.x;
  const int j = blockIdx.y * 256 + threadIdx.x;
  const float* sp = &sege[((size_t)i * 512 + j) * 16];
  const float* mp = &amask[((size_t)i * 512 + j) * 8];
  float se[16], mk[8];
#pragma unroll
  for (int q = 0; q < 4; ++q) {
    const float4 f = *(const float4*)(sp + q * 4);
    se[q * 4 + 0] = f.x; se[q * 4 + 1] = f.y; se[q * 4 + 2] = f.z; se[q * 4 + 3] = f.w;
  }
#pragma unroll
  for (int q = 0; q < 2; ++q) {
    const float4 f = *(const float4*)(mp + q * 4);
    mk[q * 4 + 0] = f.x; mk[q * 4 + 1] = f.y; mk[q * 4 + 2] = f.z; mk[q * 4 + 3] = f.w;
  }
#pragma unroll
  for (int b = 0; b < 8; ++b) {
    const u32 pk = (u32)f2bf(se[b * 2]) | ((u32)f2bf(se[b * 2 + 1]) << 16);
    const size_t plane = ((size_t)b * 512 + i) * 512 + j;
    *(u32*)&SE4[plane * 2] = pk;
    MK[plane] = f2bf(BIGNUM * mk[b]);
  }
}

// ---------------- e_s = (q + r_s_bias) . seg_mat[s], s in {0,1} ----------------
__global__ __launch_bounds__(256)
void seg_e_kernel(const u16* __restrict__ Qh, const float* __restrict__ rsb,
                  const float* __restrict__ segm, float* __restrict__ E) {
  const int gt = blockIdx.x * 256 + threadIdx.x;  // gt = (i*BSZ+b)*NHEAD + n
  const int i = gt >> 7, bb = (gt >> 4) & 7, n = gt & 15;
  const size_t base = (((size_t)bb * 16 + n) * 512 + i) * 64;
  float e0 = 0.f, e1 = 0.f;
#pragma unroll
  for (int u8 = 0; u8 < 8; ++u8) {
    const uint4 qv = *(const uint4*)&Qh[base + u8 * 8];
    float qf[8];
    bf8_to_f(qv, qf);
#pragma unroll
    for (int w = 0; w < 8; ++w) {
      const int d = u8 * 8 + w;
      const float q = qf[w] + rsb[n * HDIM + d];
      e0 += q * segm[n * HDIM + d];
      e1 += q * segm[HIDN + n * HDIM + d];
    }
  }
  E[(size_t)gt * 2 + 0] = e0;
  E[(size_t)gt * 2 + 1] = e1;
}

// ---------------- MFMA fused attention: fragment-major coalesced operands -------------
__global__ __launch_bounds__(256)
void attn_mfma(const u16* __restrict__ Qh, const u16* __restrict__ Kf,
               const u16* __restrict__ Vf, const u16* __restrict__ Krf,
               const float* __restrict__ E, const u16* __restrict__ SE4,
               const u16* __restrict__ MK, const float* __restrict__ rwb,
               const float* __restrict__ rrb, u16* __restrict__ AOb) {
  __shared__ u16 Pl[4][16 * 64];
  const int id = blockIdx.x;
  const int b = id & 7, n = (id >> 3) & 15;
  const int i0 = (id >> 7) * 64;
  const int bn = b * 16 + n;
  const int t = threadIdx.x, wv = t >> 6, lane = t & 63;
  const int l15 = lane & 15, g = lane >> 4;
  const int irow0 = i0 + wv * 16;
  u16* Pw = Pl[wv];
  const int bn64 = bn * 64;

  bf16x8 qcf[2], qrf[2];
#pragma unroll
  for (int h = 0; h < 2; ++h) {
    const int d0 = 32 * h + g * 8;
    const uint4 qv = *(const uint4*)&Qh[((size_t)bn * 512 + irow0 + l15) * 64 + d0];
    float qf[8]; bf8_to_f(qv, qf);
    union { u16 us[8]; bf16x8 v; } ua, ub;
#pragma unroll
    for (int w = 0; w < 8; ++w) {
      ua.us[w] = f2bf((qf[w] + rwb[n * HDIM + d0 + w]) * SCALE_F);
      ub.us[w] = f2bf((qf[w] + rrb[n * HDIM + d0 + w]) * SCALE_F);
    }
    qcf[h] = ua.v; qrf[h] = ub.v;
  }

  float e0v[4], e1v[4], lrun[4];
  f32x4 accO[4];
#pragma unroll
  for (int r = 0; r < 4; ++r) {
    const int i = irow0 + 4 * g + r;
    const float2 ee = *(const float2*)&E[((size_t)(i * BSZ + b) * NHEAD + n) * 2];
    e0v[r] = ee.x * SCALE_F; e1v[r] = ee.y * SCALE_F;
    lrun[r] = 0.f;
  }
#pragma unroll
  for (int c = 0; c < 4; ++c) accO[c] = (f32x4){0.f, 0.f, 0.f, 0.f};

  for (int jb = 0; jb < I_LEN; jb += 64) {
    u32 sev[4][4]; u16 mkv[4][4];
#pragma unroll
    for (int c = 0; c < 4; ++c)
#pragma unroll
      for (int r = 0; r < 4; ++r) {
        const size_t plane = ((size_t)b * 512 + (irow0 + 4 * g + r)) * 512 + jb + 16 * c + l15;
        sev[c][r] = *(const u32*)&SE4[plane * 2];
        mkv[c][r] = MK[plane];
      }
    bf16x8 vf[4][2];
#pragma unroll
    for (int c = 0; c < 4; ++c) {
      const u16* vp = &Vf[((((size_t)bn * 8 + (jb >> 6)) * 4 + c) * 2) * 512 + lane * 8];
      vf[c][0] = *(const bf16x8*)vp;
      vf[c][1] = *(const bf16x8*)(vp + 512);
    }
    f32x4 S[4];
#pragma unroll
    for (int c = 0; c < 4; ++c) S[c] = (f32x4){0.f, 0.f, 0.f, 0.f};
#pragma unroll
    for (int c = 0; c < 4; ++c) {
      const u16* kp = &Kf[(((size_t)bn * 32 + (jb >> 4) + c) * 2) * 512 + lane * 8];
      S[c] = __builtin_amdgcn_mfma_f32_16x16x32_bf16(qcf[0], *(const bf16x8*)kp, S[c], 0, 0, 0);
      S[c] = __builtin_amdgcn_mfma_f32_16x16x32_bf16(qcf[1], *(const bf16x8*)(kp + 512), S[c], 0, 0, 0);
    }
    const int tb = (jb + 496 - irow0) >> 4;
    f32x4 T[5];
#pragma unroll
    for (int c = 0; c < 5; ++c) T[c] = (f32x4){0.f, 0.f, 0.f, 0.f};
#pragma unroll
    for (int c = 0; c < 5; ++c) {
      const u16* kp = &Krf[(((size_t)bn * 64 + tb + c) * 2) * 512 + lane * 8];
      T[c] = __builtin_amdgcn_mfma_f32_16x16x32_bf16(qrf[0], *(const bf16x8*)kp, T[c], 0, 0, 0);
      T[c] = __builtin_amdgcn_mfma_f32_16x16x32_bf16(qrf[1], *(const bf16x8*)(kp + 512), T[c], 0, 0, 0);
    }
    float bd[4][4];
#pragma unroll
    for (int r = 0; r < 4; ++r) {
      const int ii = 4 * g + r;
      const int pos = (lane & 48) | ((l15 - ii) & 15);
      float bp[5];
#pragma unroll
      for (int c = 0; c < 5; ++c) bp[c] = __shfl(T[c][r], pos, 64);
      const bool sel = l15 >= ii;
#pragma unroll
      for (int c = 0; c < 4; ++c) bd[c][r] = sel ? bp[c + 1] : bp[c];
    }
#pragma unroll
    for (int c = 0; c < 4; ++c)
#pragma unroll
      for (int r = 0; r < 4; ++r) {
        const u32 sev_ = sev[c][r];
        const float s = S[c][r] + bd[c][r] + bflo(sev_) * e0v[r] + bfhi(sev_) * e1v[r]
                        - bflo((u32)mkv[c][r]);
        const float p = __expf(s);
        S[c][r] = p;
        lrun[r] += p;
      }
#pragma unroll
    for (int c = 0; c < 4; ++c)
#pragma unroll
      for (int r = 0; r < 4; ++r) {
        const int ii = 4 * g + r;
        Pw[ii * 64 + ((16 * c + l15) ^ ((ii & 7) << 3))] = f2bf(S[c][r]);
      }
    const bf16x8 pa0 = *(const bf16x8*)&Pw[l15 * 64 + ((g * 8) ^ ((l15 & 7) << 3))];
    const bf16x8 pa1 = *(const bf16x8*)&Pw[l15 * 64 + ((32 + g * 8) ^ ((l15 & 7) << 3))];
#pragma unroll
    for (int c = 0; c < 4; ++c) {
      accO[c] = __builtin_amdgcn_mfma_f32_16x16x32_bf16(pa0, vf[c][0], accO[c], 0, 0, 0);
      accO[c] = __builtin_amdgcn_mfma_f32_16x16x32_bf16(pa1, vf[c][1], accO[c], 0, 0, 0);
    }
  }
#pragma unroll
  for (int r = 0; r < 4; ++r) {
#pragma unroll
    for (int o = 1; o < 16; o <<= 1) lrun[r] += __shfl_xor(lrun[r], o);
  }
#pragma unroll
  for (int c = 0; c < 4; ++c)
#pragma unroll
    for (int r = 0; r < 4; ++r) {
      const int ii = 4 * g + r;
      AOb[(size_t)(irow0 + ii) * 8192 + bn64 + 16 * c + l15] = f2bf(accO[c][r] / lrun[r]);
    }
}

// ---------------- O-projection GEMM: XCD-grouped 1-D grid (512 blocks) ----------------
// id = (y&7) + 8*(x + 8*(y>>3)): the 8 x-blocks sharing a 64-row A-tile land on one XCD.
__global__ __launch_bounds__(256)
void oproj_gemm(const u16* __restrict__ A, const u16* __restrict__ Wob,
                const float* __restrict__ Res, float* __restrict__ C) {
  constexpr int K = 1024;
  __shared__ u16 As[64 * 64];
  __shared__ u16 Bs[128 * 64];
  const int id = blockIdx.x;
  const int low = id & 7;
  const int rest = id >> 3;
  const int bx = rest & 7;
  const int by = low + 8 * (rest >> 3);    // 0..63
  const int bm = by * 64, bn = bx * 128;
  const int tid = threadIdx.x, wv = tid >> 6, lane = tid & 63;
  const int l15 = lane & 15, g = lane >> 4;
  const int wr = wv >> 1, wc = wv & 1;

  f32x4 acc[2][4];
#pragma unroll
  for (int m = 0; m < 2; ++m)
#pragma unroll
    for (int n = 0; n < 4; ++n) acc[m][n] = (f32x4){0.f, 0.f, 0.f, 0.f};

  for (int k0 = 0; k0 < K; k0 += 64) {
#pragma unroll
    for (int p = 0; p < 2; ++p) {
      const int unit = (wv * 2 + p) * 64 + lane;
      const int row = unit >> 3, up = unit & 7, c = up ^ (row & 7);
      GLOAD_LDS16(&A[(size_t)(bm + row) * K + k0 + c * 8], &As[unit * 8]);
    }
#pragma unroll
    for (int p = 0; p < 4; ++p) {
      const int unit = (wv * 4 + p) * 64 + lane;
      const int row = unit >> 3, up = unit & 7, c = up ^ (row & 7);
      GLOAD_LDS16(&Wob[(size_t)(bn + row) * K + k0 + c * 8], &Bs[unit * 8]);
    }
    __syncthreads();
#pragma unroll
    for (int h = 0; h < 2; ++h) {
      bf16x8 af[2], bfv[4];
#pragma unroll
      for (int m = 0; m < 2; ++m) {
        const int row = wr * 32 + m * 16 + l15;
        af[m] = *(const bf16x8*)&As[row * 64 + ((h * 4 + g) ^ (row & 7)) * 8];
      }
#pragma unroll
      for (int n = 0; n < 4; ++n) {
        const int col = wc * 64 + n * 16 + l15;
        bfv[n] = *(const bf16x8*)&Bs[col * 64 + ((h * 4 + g) ^ (col & 7)) * 8];
      }
#pragma unroll
      for (int m = 0; m < 2; ++m)
#pragma unroll
        for (int n = 0; n < 4; ++n)
          acc[m][n] = __builtin_amdgcn_mfma_f32_16x16x32_bf16(af[m], bfv[n], acc[m][n], 0, 0, 0);
    }
    __syncthreads();
  }
#pragma unroll
  for (int m = 0; m < 2; ++m) {
    const int row0 = bm + wr * 32 + m * 16 + g * 4;
#pragma unroll
    for (int nf = 0; nf < 4; ++nf) {
      const int col = bn + wc * 64 + nf * 16 + l15;
#pragma unroll
      for (int r = 0; r < 4; ++r) {
        const int row = row0 + r;
        C[(size_t)row * 1024 + col] = acc[m][nf][r] + Res[(size_t)row * 1024 + col];
      }
    }
  }
}

// ---------------- LayerNorm over HID=1024, one block per (i,b) row ----------------
__global__ __launch_bounds__(256)
void ln_kernel(const float* __restrict__ X, const float* __restrict__ gam,
               const float* __restrict__ bet, float* __restrict__ out) {
  const int row = blockIdx.x, t = threadIdx.x;
  const float4 x4 = *(const float4*)&X[(size_t)row * HIDN + t * 4];
  float s  = x4.x + x4.y + x4.z + x4.w;
  float sq = x4.x * x4.x + x4.y * x4.y + x4.z * x4.z + x4.w * x4.w;
#pragma unroll
  for (int o = 32; o >= 1; o >>= 1) { s += __shfl_xor(s, o); sq += __shfl_xor(sq, o); }
  __shared__ float red[8];
  const int wv = t >> 6;
  if ((t & 63) == 0) { red[wv * 2] = s; red[wv * 2 + 1] = sq; }
  __syncthreads();
  s  = red[0] + red[2] + red[4] + red[6];
  sq = red[1] + red[3] + red[5] + red[7];
  const float mu  = s * (1.f / HIDN);
  const float var = sq * (1.f / HIDN) - mu * mu;
  const float rs  = rsqrtf(var + LN_EPS);
  const float4 g4 = *(const float4*)&gam[t * 4];
  const float4 b4 = *(const float4*)&bet[t * 4];
  float4 o4;
  o4.x = (x4.x - mu) * rs * g4.x + b4.x;
  o4.y = (x4.y - mu) * rs * g4.y + b4.y;
  o4.z = (x4.z - mu) * rs * g4.z + b4.z;
  o4.w = (x4.w - mu) * rs * g4.w + b4.w;
  *(float4*)&out[(size_t)row * HIDN + t * 4] = o4;
}

extern "C" void kernel_launch(void* const* d_in, const int* in_sizes, int n_in,
                              void* d_out, int out_size, void* d_ws, size_t ws_size,
                              hipStream_t stream) {
  (void)in_sizes; (void)n_in; (void)out_size; (void)ws_size;
  const float* hidden = (const float*)d_in[0];
  const float* pos    = (const float*)d_in[1];
  const float* sege   = (const float*)d_in[2];
  const float* amask  = (const float*)d_in[3];
  const float* qw     = (const float*)d_in[4];
  const float* kw     = (const float*)d_in[5];
  const float* vw     = (const float*)d_in[6];
  const float* rw     = (const float*)d_in[7];
  const float* ow     = (const float*)d_in[8];
  const float* rwb    = (const float*)d_in[9];
  const float* rrb    = (const float*)d_in[10];
  const float* rsb    = (const float*)d_in[11];
  const float* segm   = (const float*)d_in[12];
  const float* gam    = (const float*)d_in[13];
  const float* bet    = (const float*)d_in[14];
  float* out = (float*)d_out;
  char* ws = (char*)d_ws;

  const size_t MiB = 1ull << 20;
  u16*   Wqt = (u16*)(ws);
  u16*   Wkt = (u16*)(ws + 2 * MiB);
  u16*   Wvt = (u16*)(ws + 4 * MiB);
  u16*   Wrt = (u16*)(ws + 6 * MiB);
  u16*   AOb = (u16*)(ws);
  u16*   Qh  = (u16*)(ws + 8 * MiB);
  u16*   Kf  = (u16*)(ws + 16 * MiB);
  u16*   Vf  = (u16*)(ws + 24 * MiB);
  u16*   Krf = (u16*)(ws + 32 * MiB);
  float* X   = (float*)(ws + 32 * MiB);
  u16*   Hb  = (u16*)(ws + 48 * MiB);
  u16*   SE4 = (u16*)(ws + 48 * MiB);
  u16*   MK  = (u16*)(ws + 56 * MiB);
  float* E   = (float*)(ws + 60 * MiB);
  u16*   Wob = (u16*)(ws + 60 * MiB + 512 * 1024);

  wtrans_kernel<<<dim3(16, 16, 4), 256, 0, stream>>>(qw, kw, vw, rw, Wqt, Wkt, Wvt, Wrt);
  hcvt_kernel<<<2560, 256, 0, stream>>>(hidden, ow, Hb, Wob);
  proj_gemm<<<1280, 256, 0, stream>>>(Hb, pos, Wqt, Wkt, Wvt, Wrt, Qh, Kf, Vf, Krf);
  vrepack_kernel<<<dim3(128, 8), 256, 0, stream>>>(Vf);
  setrans_kernel<<<dim3(512, 2), 256, 0, stream>>>(sege, amask, SE4, MK);
  seg_e_kernel<<<256, 256, 0, stream>>>(Qh, rsb, segm, E);
  attn_mfma<<<1024, 256, 0, stream>>>(Qh, Kf, Vf, Krf, E, SE4, MK, rwb, rrb, AOb);
  oproj_gemm<<<512, 256, 0, stream>>>(AOb, Wob, hidden, X);
  ln_kernel<<<4096, 256, 0, stream>>>(X, gam, bet, out);
}

// Round 13
// 165.199 us; speedup vs baseline: 1.4655x; 1.0215x over previous
//
#include <hip/hip_runtime.h>
#include <hip/hip_bf16.h>

#define I_LEN 512
#define BSZ   8
#define HIDN  1024
#define NHEAD 16
#define HDIM  64
#define PLEN_ 1024
#define SCALE_F 0.125f
#define BIGNUM 1e30f
#define LN_EPS 1e-5f

typedef unsigned int   u32;
typedef unsigned short u16;
typedef __attribute__((ext_vector_type(8))) short bf16x8;
typedef __attribute__((ext_vector_type(4))) float f32x4;

__device__ __forceinline__ float bflo(u32 w) { return __uint_as_float(w << 16); }
__device__ __forceinline__ float bfhi(u32 w) { return __uint_as_float(w & 0xffff0000u); }
__device__ __forceinline__ u16 f2bf(float x) {
  u32 u = __float_as_uint(x);
  return (u16)((u + 0x7fffu + ((u >> 16) & 1u)) >> 16);
}
__device__ __forceinline__ void bf8_to_f(const uint4 v, float* f) {
  f[0] = bflo(v.x); f[1] = bfhi(v.x);
  f[2] = bflo(v.y); f[3] = bfhi(v.y);
  f[4] = bflo(v.z); f[5] = bfhi(v.z);
  f[6] = bflo(v.w); f[7] = bfhi(v.w);
}

#define GLOAD_LDS16(gp, lp) __builtin_amdgcn_global_load_lds( \
    (const __attribute__((address_space(1))) void*)(gp),      \
    (__attribute__((address_space(3))) void*)(lp), 16, 0, 0)

// ---------------- fused projection GEMM: 5-way z, XCD-grouped, 2-PHASE double-buffer ----
// Per K-step: issue next-tile global_load_lds FIRST, then compute current tile, then one
// __syncthreads (= vmcnt(0)+barrier): loads overlap the 32 MFMAs (T3-min recipe).
__global__ __launch_bounds__(256)
void proj_gemm(const u16* __restrict__ Hb, const float* __restrict__ pos,
               const u16* __restrict__ Wqt, const u16* __restrict__ Wkt,
               const u16* __restrict__ Wvt, const u16* __restrict__ Wrt,
               u16* __restrict__ Qh, u16* __restrict__ Kf,
               u16* __restrict__ Vh, u16* __restrict__ Krf) {
  constexpr int K = 1024;
  __shared__ union {
    struct { u16 As[2 * 8192]; u16 Bs[2 * 8192]; } st;  // 64 KB double-buffered staging
    u16 epi[4][64 * 68];                                 // per-wave head-contig epi
    u16 epiK[128 * 137];                                 // block-wide fragment epi
  } sm;
  u16* As = sm.st.As;
  u16* Bs = sm.st.Bs;
  // XCD-grouped decode
  const int id = blockIdx.x;
  const int low = id & 7;
  const int rest = id >> 3;
  const int bx = rest & 7;
  const int grp = low + 8 * (rest >> 3);   // 0..159
  const int by = grp & 31;
  const int z = grp >> 5;
  const u16* Bt; u16* C;
  if (z == 0)      { Bt = Wqt; C = Qh;  }
  else if (z == 1) { Bt = Wkt; C = Kf;  }
  else if (z == 2) { Bt = Wvt; C = Vh;  }
  else if (z == 3) { Bt = Wrt; C = Krf; }
  else             { Bt = Wrt; C = Krf; }
  const float* Apos = pos + (size_t)((z == 4) ? 4096 : 0) * 1024;
  const int bm = by * 128, bn = bx * 128;
  const int tid = threadIdx.x, wv = tid >> 6, lane = tid & 63;
  const int l15 = lane & 15, g = lane >> 4;
  const int wr = wv >> 1, wc = wv & 1;

#define STAGE_B_P(BUF, K0)                                                    \
  _Pragma("unroll")                                                           \
  for (int p = 0; p < 4; ++p) {                                               \
    const int unit = (wv * 4 + p) * 64 + lane;                                \
    const int row = unit >> 3, up = unit & 7, cc = up ^ (row & 7);            \
    GLOAD_LDS16(&Bt[(size_t)(bn + row) * K + (K0) + cc * 8],                  \
                &Bs[(BUF) * 8192 + unit * 8]);                                \
  }
#define STAGE_A16_P(BUF, K0)                                                  \
  _Pragma("unroll")                                                           \
  for (int p = 0; p < 4; ++p) {                                               \
    const int unit = (wv * 4 + p) * 64 + lane;                                \
    const int row = unit >> 3, up = unit & 7, cc = up ^ (row & 7);            \
    GLOAD_LDS16(&Hb[(size_t)(bm + row) * K + (K0) + cc * 8],                  \
                &As[(BUF) * 8192 + unit * 8]);                                \
  }
#define STAGE_A32_P(BUF, K0)                                                  \
  _Pragma("unroll")                                                           \
  for (int p = 0; p < 4; ++p) {                                               \
    const int unit = p * 256 + tid;                                           \
    const int row = unit >> 3, up = unit & 7, cc = up ^ (row & 7);            \
    const float* src = &Apos[(size_t)(bm + row) * K + (K0) + cc * 8];         \
    const float4 f0 = *(const float4*)src;                                    \
    const float4 f1 = *(const float4*)(src + 4);                              \
    ushort4 h0, h1;                                                           \
    h0.x = f2bf(f0.x); h0.y = f2bf(f0.y); h0.z = f2bf(f0.z); h0.w = f2bf(f0.w); \
    h1.x = f2bf(f1.x); h1.y = f2bf(f1.y); h1.z = f2bf(f1.z); h1.w = f2bf(f1.w); \
    *(ushort4*)&As[(BUF) * 8192 + unit * 8] = h0;                             \
    *(ushort4*)&As[(BUF) * 8192 + unit * 8 + 4] = h1;                         \
  }

  f32x4 acc[4][4];
#pragma unroll
  for (int m = 0; m < 4; ++m)
#pragma unroll
    for (int n = 0; n < 4; ++n) acc[m][n] = (f32x4){0.f, 0.f, 0.f, 0.f};

  // prologue: stage tile 0 into buffer 0
  STAGE_B_P(0, 0);
  if (z < 3) { STAGE_A16_P(0, 0); } else { STAGE_A32_P(0, 0); }
  __syncthreads();

  int cur = 0;
  for (int t = 0; t < 16; ++t) {
    // issue next tile into the other buffer (overlaps with compute below)
    if (t + 1 < 16) {
      const int k1 = (t + 1) * 64;
      STAGE_B_P(cur ^ 1, k1);
      if (z < 3) { STAGE_A16_P(cur ^ 1, k1); } else { STAGE_A32_P(cur ^ 1, k1); }
    }
    // compute current tile
    const u16* Ac = &As[cur * 8192];
    const u16* Bc = &Bs[cur * 8192];
#pragma unroll
    for (int h = 0; h < 2; ++h) {
      bf16x8 af[4], bfv[4];
#pragma unroll
      for (int m = 0; m < 4; ++m) {
        const int row = wr * 64 + m * 16 + l15;
        af[m] = *(const bf16x8*)&Ac[row * 64 + ((h * 4 + g) ^ (row & 7)) * 8];
      }
#pragma unroll
      for (int n = 0; n < 4; ++n) {
        const int col = wc * 64 + n * 16 + l15;
        bfv[n] = *(const bf16x8*)&Bc[col * 64 + ((h * 4 + g) ^ (col & 7)) * 8];
      }
#pragma unroll
      for (int m = 0; m < 4; ++m)
#pragma unroll
        for (int n = 0; n < 4; ++n)
          acc[m][n] = __builtin_amdgcn_mfma_f32_16x16x32_bf16(af[m], bfv[n], acc[m][n], 0, 0, 0);
    }
    __syncthreads();   // staged loads complete; all waves done reading old buffer
    cur ^= 1;
  }

  if (z == 1 || z >= 3) {
    // fragment-major epilogue: block-wide 128x137 LDS tile, then 32 coalesced 1KB runs
    u16* E128 = sm.epiK;
#pragma unroll
    for (int m = 0; m < 4; ++m)
#pragma unroll
      for (int nf = 0; nf < 4; ++nf)
#pragma unroll
        for (int r = 0; r < 4; ++r)
          E128[(wr * 64 + m * 16 + g * 4 + r) * 137 + wc * 64 + nf * 16 + l15] =
              f2bf(acc[m][nf][r]);
    __syncthreads();
    const int tK = (z == 1) ? by : (by + ((z == 4) ? 32 : 0));
    const int TS = (z == 1) ? 32 : 64;
#pragma unroll
    for (int q = 0; q < 8; ++q) {
      const int rid = wv * 8 + q;
      const int n_loc = rid >> 4, b_ = (rid >> 1) & 7, h = rid & 1;
      union { u16 us[8]; uint4 qv; } o;
#pragma unroll
      for (int e = 0; e < 8; ++e)
        o.us[e] = E128[(l15 * 8 + b_) * 137 + n_loc * 64 + h * 32 + g * 8 + e];
      const int head = bx * 2 + n_loc;
      const size_t base = (((size_t)(b_ * 16 + head) * TS + tK) * 2 + h) * 512 + lane * 8;
      *(uint4*)&C[base] = o.qv;
    }
  } else {
    // head-contig epilogue (Q, V)
    u16* slice = sm.epi[wv];
    __syncthreads();
#pragma unroll
    for (int m = 0; m < 4; ++m)
#pragma unroll
      for (int nf = 0; nf < 4; ++nf)
#pragma unroll
        for (int r = 0; r < 4; ++r)
          slice[(m * 16 + g * 4 + r) * 68 + nf * 16 + l15] = f2bf(acc[m][nf][r]);
#pragma unroll
    for (int it = 0; it < 8; ++it) {
      const int rl = it * 8 + (lane >> 3);
      const int cl = (lane & 7) * 8;
      const ushort4 a = *(const ushort4*)&slice[rl * 68 + cl];
      const ushort4 b2 = *(const ushort4*)&slice[rl * 68 + cl + 4];
      const int row = bm + wr * 64 + rl;
      const int col = bn + wc * 64 + cl;
      const size_t idx = ((size_t)((row & 7) * 16 + (col >> 6)) * 512 + (row >> 3)) * 64 + (col & 63);
      *(ushort4*)&C[idx] = a;
      *(ushort4*)&C[idx + 4] = b2;
    }
  }
}

// ---------------- V repack (IN-PLACE): Vh[bn][j][d] -> Vf[bn][j64][c][h][lane][8] -------
__global__ __launch_bounds__(256)
void vrepack_kernel(u16* __restrict__ V) {
  __shared__ u16 tile[64][72];
  const int bn = blockIdx.x, slab = blockIdx.y;
  const int t = threadIdx.x;
  const size_t base = ((size_t)bn * 8 + slab) * 4096;
  {
    const int jl = t >> 2, c0 = (t & 3) * 16;
    const uint4 v0 = *(const uint4*)&V[base + jl * 64 + c0];
    const uint4 v1 = *(const uint4*)&V[base + jl * 64 + c0 + 8];
    *(uint4*)&tile[jl][c0] = v0;
    *(uint4*)&tile[jl][c0 + 8] = v1;
  }
  __syncthreads();
  const int lane = t & 63, g = lane >> 4, l15 = lane & 15;
#pragma unroll
  for (int w = 0; w < 2; ++w) {
    const int run = w * 4 + (t >> 6);
    const int c = run >> 1, h = run & 1;
    union { u16 us[8]; uint4 qv; } o;
#pragma unroll
    for (int e = 0; e < 8; ++e) o.us[e] = tile[h * 32 + g * 8 + e][16 * c + l15];
    *(uint4*)&V[base + run * 512 + lane * 8] = o.qv;
  }
}

// ---------------- hidden + ow f32 -> bf16 ----------------
__global__ __launch_bounds__(256)
void hcvt_kernel(const float* __restrict__ hidden, const float* __restrict__ ow,
                 u16* __restrict__ Hb, u16* __restrict__ Wob) {
  const size_t i = (size_t)blockIdx.x * 256 + threadIdx.x;
  const float* src; u16* dst; size_t off;
  if (i < 524288) { src = hidden; dst = Hb; off = i * 8; }
  else            { src = ow;     dst = Wob; off = (i - 524288) * 8; }
  const float4 a = *(const float4*)&src[off];
  const float4 b = *(const float4*)&src[off + 4];
  ushort4 o0, o1;
  o0.x = f2bf(a.x); o0.y = f2bf(a.y); o0.z = f2bf(a.z); o0.w = f2bf(a.w);
  o1.x = f2bf(b.x); o1.y = f2bf(b.y); o1.z = f2bf(b.z); o1.w = f2bf(b.w);
  *(ushort4*)&dst[off] = o0;
  *(ushort4*)&dst[off + 4] = o1;
}

// ---------------- weight transpose+cvt: W[h][nd] f32 -> T[nd][h] bf16 ----------------
__global__ __launch_bounds__(256)
void wtrans_kernel(const float* __restrict__ W0, const float* __restrict__ W1,
                   const float* __restrict__ W2, const float* __restrict__ W3,
                   u16* __restrict__ T0, u16* __restrict__ T1,
                   u16* __restrict__ T2, u16* __restrict__ T3) {
  __shared__ u16 tile[64][72];
  const int z = blockIdx.z;
  const float* W = (z == 0) ? W0 : ((z == 1) ? W1 : ((z == 2) ? W2 : W3));
  u16* T = (z == 0) ? T0 : ((z == 1) ? T1 : ((z == 2) ? T2 : T3));
  const int h0 = blockIdx.y * 64, nd0 = blockIdx.x * 64;
  const int t = threadIdx.x;
  {
    const int hr = t >> 2, c0 = (t & 3) * 16;
#pragma unroll
    for (int q = 0; q < 4; ++q) {
      const float4 f = *(const float4*)&W[(size_t)(h0 + hr) * 1024 + nd0 + c0 + q * 4];
      tile[hr][c0 + q * 4 + 0] = f2bf(f.x);
      tile[hr][c0 + q * 4 + 1] = f2bf(f.y);
      tile[hr][c0 + q * 4 + 2] = f2bf(f.z);
      tile[hr][c0 + q * 4 + 3] = f2bf(f.w);
    }
  }
  __syncthreads();
  const int ndr = t >> 2, hc0 = (t & 3) * 16;
  union { u16 us[16]; uint4 qv[2]; } o;
#pragma unroll
  for (int e = 0; e < 16; ++e) o.us[e] = tile[hc0 + e][ndr];
  uint4* dst = (uint4*)&T[(size_t)(nd0 + ndr) * 1024 + h0 + hc0];
  dst[0] = o.qv[0]; dst[1] = o.qv[1];
}

// -------- sege+mask transpose: SE4[b][i][j] packed 2xbf16; MK[b][i][j] bf16 BIG*mask ---
__global__ __launch_bounds__(256)
void setrans_kernel(const float* __restrict__ sege, const float* __restrict__ amask,
                    u16* __restrict__ SE4, u16* __restrict__ MK) {
  const int i = blockIdx.x;
  const int j = blockIdx.y * 256 + threadIdx.x;
  const float* sp = &sege[((size_t)i * 512 + j) * 16];
  const float* mp = &amask[((size_t)i * 512 + j) * 8];
  float se[16], mk[8];
#pragma unroll
  for (int q = 0; q < 4; ++q) {
    const float4 f = *(const float4*)(sp + q * 4);
    se[q * 4 + 0] = f.x; se[q * 4 + 1] = f.y; se[q * 4 + 2] = f.z; se[q * 4 + 3] = f.w;
  }
#pragma unroll
  for (int q = 0; q < 2; ++q) {
    const float4 f = *(const float4*)(mp + q * 4);
    mk[q * 4 + 0] = f.x; mk[q * 4 + 1] = f.y; mk[q * 4 + 2] = f.z; mk[q * 4 + 3] = f.w;
  }
#pragma unroll
  for (int b = 0; b < 8; ++b) {
    const u32 pk = (u32)f2bf(se[b * 2]) | ((u32)f2bf(se[b * 2 + 1]) << 16);
    const size_t plane = ((size_t)b * 512 + i) * 512 + j;
    *(u32*)&SE4[plane * 2] = pk;
    MK[plane] = f2bf(BIGNUM * mk[b]);
  }
}

// ---------------- e_s = (q + r_s_bias) . seg_mat[s], s in {0,1} ----------------
__global__ __launch_bounds__(256)
void seg_e_kernel(const u16* __restrict__ Qh, const float* __restrict__ rsb,
                  const float* __restrict__ segm, float* __restrict__ E) {
  const int gt = blockIdx.x * 256 + threadIdx.x;  // gt = (i*BSZ+b)*NHEAD + n
  const int i = gt >> 7, bb = (gt >> 4) & 7, n = gt & 15;
  const size_t base = (((size_t)bb * 16 + n) * 512 + i) * 64;
  float e0 = 0.f, e1 = 0.f;
#pragma unroll
  for (int u8 = 0; u8 < 8; ++u8) {
    const uint4 qv = *(const uint4*)&Qh[base + u8 * 8];
    float qf[8];
    bf8_to_f(qv, qf);
#pragma unroll
    for (int w = 0; w < 8; ++w) {
      const int d = u8 * 8 + w;
      const float q = qf[w] + rsb[n * HDIM + d];
      e0 += q * segm[n * HDIM + d];
      e1 += q * segm[HIDN + n * HDIM + d];
    }
  }
  E[(size_t)gt * 2 + 0] = e0;
  E[(size_t)gt * 2 + 1] = e1;
}

// ---------------- MFMA fused attention: fragment-major coalesced operands -------------
__global__ __launch_bounds__(256)
void attn_mfma(const u16* __restrict__ Qh, const u16* __restrict__ Kf,
               const u16* __restrict__ Vf, const u16* __restrict__ Krf,
               const float* __restrict__ E, const u16* __restrict__ SE4,
               const u16* __restrict__ MK, const float* __restrict__ rwb,
               const float* __restrict__ rrb, u16* __restrict__ AOb) {
  __shared__ u16 Pl[4][16 * 64];
  const int id = blockIdx.x;
  const int b = id & 7, n = (id >> 3) & 15;
  const int i0 = (id >> 7) * 64;
  const int bn = b * 16 + n;
  const int t = threadIdx.x, wv = t >> 6, lane = t & 63;
  const int l15 = lane & 15, g = lane >> 4;
  const int irow0 = i0 + wv * 16;
  u16* Pw = Pl[wv];
  const int bn64 = bn * 64;

  bf16x8 qcf[2], qrf[2];
#pragma unroll
  for (int h = 0; h < 2; ++h) {
    const int d0 = 32 * h + g * 8;
    const uint4 qv = *(const uint4*)&Qh[((size_t)bn * 512 + irow0 + l15) * 64 + d0];
    float qf[8]; bf8_to_f(qv, qf);
    union { u16 us[8]; bf16x8 v; } ua, ub;
#pragma unroll
    for (int w = 0; w < 8; ++w) {
      ua.us[w] = f2bf((qf[w] + rwb[n * HDIM + d0 + w]) * SCALE_F);
      ub.us[w] = f2bf((qf[w] + rrb[n * HDIM + d0 + w]) * SCALE_F);
    }
    qcf[h] = ua.v; qrf[h] = ub.v;
  }

  float e0v[4], e1v[4], lrun[4];
  f32x4 accO[4];
#pragma unroll
  for (int r = 0; r < 4; ++r) {
    const int i = irow0 + 4 * g + r;
    const float2 ee = *(const float2*)&E[((size_t)(i * BSZ + b) * NHEAD + n) * 2];
    e0v[r] = ee.x * SCALE_F; e1v[r] = ee.y * SCALE_F;
    lrun[r] = 0.f;
  }
#pragma unroll
  for (int c = 0; c < 4; ++c) accO[c] = (f32x4){0.f, 0.f, 0.f, 0.f};

  for (int jb = 0; jb < I_LEN; jb += 64) {
    u32 sev[4][4]; u16 mkv[4][4];
#pragma unroll
    for (int c = 0; c < 4; ++c)
#pragma unroll
      for (int r = 0; r < 4; ++r) {
        const size_t plane = ((size_t)b * 512 + (irow0 + 4 * g + r)) * 512 + jb + 16 * c + l15;
        sev[c][r] = *(const u32*)&SE4[plane * 2];
        mkv[c][r] = MK[plane];
      }
    bf16x8 vf[4][2];
#pragma unroll
    for (int c = 0; c < 4; ++c) {
      const u16* vp = &Vf[((((size_t)bn * 8 + (jb >> 6)) * 4 + c) * 2) * 512 + lane * 8];
      vf[c][0] = *(const bf16x8*)vp;
      vf[c][1] = *(const bf16x8*)(vp + 512);
    }
    f32x4 S[4];
#pragma unroll
    for (int c = 0; c < 4; ++c) S[c] = (f32x4){0.f, 0.f, 0.f, 0.f};
#pragma unroll
    for (int c = 0; c < 4; ++c) {
      const u16* kp = &Kf[(((size_t)bn * 32 + (jb >> 4) + c) * 2) * 512 + lane * 8];
      S[c] = __builtin_amdgcn_mfma_f32_16x16x32_bf16(qcf[0], *(const bf16x8*)kp, S[c], 0, 0, 0);
      S[c] = __builtin_amdgcn_mfma_f32_16x16x32_bf16(qcf[1], *(const bf16x8*)(kp + 512), S[c], 0, 0, 0);
    }
    const int tb = (jb + 496 - irow0) >> 4;
    f32x4 T[5];
#pragma unroll
    for (int c = 0; c < 5; ++c) T[c] = (f32x4){0.f, 0.f, 0.f, 0.f};
#pragma unroll
    for (int c = 0; c < 5; ++c) {
      const u16* kp = &Krf[(((size_t)bn * 64 + tb + c) * 2) * 512 + lane * 8];
      T[c] = __builtin_amdgcn_mfma_f32_16x16x32_bf16(qrf[0], *(const bf16x8*)kp, T[c], 0, 0, 0);
      T[c] = __builtin_amdgcn_mfma_f32_16x16x32_bf16(qrf[1], *(const bf16x8*)(kp + 512), T[c], 0, 0, 0);
    }
    float bd[4][4];
#pragma unroll
    for (int r = 0; r < 4; ++r) {
      const int ii = 4 * g + r;
      const int pos = (lane & 48) | ((l15 - ii) & 15);
      float bp[5];
#pragma unroll
      for (int c = 0; c < 5; ++c) bp[c] = __shfl(T[c][r], pos, 64);
      const bool sel = l15 >= ii;
#pragma unroll
      for (int c = 0; c < 4; ++c) bd[c][r] = sel ? bp[c + 1] : bp[c];
    }
#pragma unroll
    for (int c = 0; c < 4; ++c)
#pragma unroll
      for (int r = 0; r < 4; ++r) {
        const u32 sev_ = sev[c][r];
        const float s = S[c][r] + bd[c][r] + bflo(sev_) * e0v[r] + bfhi(sev_) * e1v[r]
                        - bflo((u32)mkv[c][r]);
        const float p = __expf(s);
        S[c][r] = p;
        lrun[r] += p;
      }
#pragma unroll
    for (int c = 0; c < 4; ++c)
#pragma unroll
      for (int r = 0; r < 4; ++r) {
        const int ii = 4 * g + r;
        Pw[ii * 64 + ((16 * c + l15) ^ ((ii & 7) << 3))] = f2bf(S[c][r]);
      }
    const bf16x8 pa0 = *(const bf16x8*)&Pw[l15 * 64 + ((g * 8) ^ ((l15 & 7) << 3))];
    const bf16x8 pa1 = *(const bf16x8*)&Pw[l15 * 64 + ((32 + g * 8) ^ ((l15 & 7) << 3))];
#pragma unroll
    for (int c = 0; c < 4; ++c) {
      accO[c] = __builtin_amdgcn_mfma_f32_16x16x32_bf16(pa0, vf[c][0], accO[c], 0, 0, 0);
      accO[c] = __builtin_amdgcn_mfma_f32_16x16x32_bf16(pa1, vf[c][1], accO[c], 0, 0, 0);
    }
  }
#pragma unroll
  for (int r = 0; r < 4; ++r) {
#pragma unroll
    for (int o = 1; o < 16; o <<= 1) lrun[r] += __shfl_xor(lrun[r], o);
  }
#pragma unroll
  for (int c = 0; c < 4; ++c)
#pragma unroll
    for (int r = 0; r < 4; ++r) {
      const int ii = 4 * g + r;
      AOb[(size_t)(irow0 + ii) * 8192 + bn64 + 16 * c + l15] = f2bf(accO[c][r] / lrun[r]);
    }
}

// ---------------- O-projection GEMM: XCD-grouped, 2-PHASE double-buffer ----------------
__global__ __launch_bounds__(256)
void oproj_gemm(const u16* __restrict__ A, const u16* __restrict__ Wob,
                const float* __restrict__ Res, float* __restrict__ C) {
  constexpr int K = 1024;
  __shared__ u16 As[2 * 4096];
  __shared__ u16 Bs[2 * 8192];
  const int id = blockIdx.x;
  const int low = id & 7;
  const int rest = id >> 3;
  const int bx = rest & 7;
  const int by = low + 8 * (rest >> 3);    // 0..63
  const int bm = by * 64, bn = bx * 128;
  const int tid = threadIdx.x, wv = tid >> 6, lane = tid & 63;
  const int l15 = lane & 15, g = lane >> 4;
  const int wr = wv >> 1, wc = wv & 1;

#define STAGE_O(BUF, K0)                                                      \
  _Pragma("unroll")                                                           \
  for (int p = 0; p < 2; ++p) {                                               \
    const int unit = (wv * 2 + p) * 64 + lane;                                \
    const int row = unit >> 3, up = unit & 7, cc = up ^ (row & 7);            \
    GLOAD_LDS16(&A[(size_t)(bm + row) * K + (K0) + cc * 8],                   \
                &As[(BUF) * 4096 + unit * 8]);                                \
  }                                                                           \
  _Pragma("unroll")                                                           \
  for (int p = 0; p < 4; ++p) {                                               \
    const int unit = (wv * 4 + p) * 64 + lane;                                \
    const int row = unit >> 3, up = unit & 7, cc = up ^ (row & 7);            \
    GLOAD_LDS16(&Wob[(size_t)(bn + row) * K + (K0) + cc * 8],                 \
                &Bs[(BUF) * 8192 + unit * 8]);                                \
  }

  f32x4 acc[2][4];
#pragma unroll
  for (int m = 0; m < 2; ++m)
#pragma unroll
    for (int n = 0; n < 4; ++n) acc[m][n] = (f32x4){0.f, 0.f, 0.f, 0.f};

  STAGE_O(0, 0);
  __syncthreads();
  int cur = 0;
  for (int t = 0; t < 16; ++t) {
    if (t + 1 < 16) { STAGE_O(cur ^ 1, (t + 1) * 64); }
    const u16* Ac = &As[cur * 4096];
    const u16* Bc = &Bs[cur * 8192];
#pragma unroll
    for (int h = 0; h < 2; ++h) {
      bf16x8 af[2], bfv[4];
#pragma unroll
      for (int m = 0; m < 2; ++m) {
        const int row = wr * 32 + m * 16 + l15;
        af[m] = *(const bf16x8*)&Ac[row * 64 + ((h * 4 + g) ^ (row & 7)) * 8];
      }
#pragma unroll
      for (int n = 0; n < 4; ++n) {
        const int col = wc * 64 + n * 16 + l15;
        bfv[n] = *(const bf16x8*)&Bc[col * 64 + ((h * 4 + g) ^ (col & 7)) * 8];
      }
#pragma unroll
      for (int m = 0; m < 2; ++m)
#pragma unroll
        for (int n = 0; n < 4; ++n)
          acc[m][n] = __builtin_amdgcn_mfma_f32_16x16x32_bf16(af[m], bfv[n], acc[m][n], 0, 0, 0);
    }
    __syncthreads();
    cur ^= 1;
  }
#pragma unroll
  for (int m = 0; m < 2; ++m) {
    const int row0 = bm + wr * 32 + m * 16 + g * 4;
#pragma unroll
    for (int nf = 0; nf < 4; ++nf) {
      const int col = bn + wc * 64 + nf * 16 + l15;
#pragma unroll
      for (int r = 0; r < 4; ++r) {
        const int row = row0 + r;
        C[(size_t)row * 1024 + col] = acc[m][nf][r] + Res[(size_t)row * 1024 + col];
      }
    }
  }
}

// ---------------- LayerNorm over HID=1024, one block per (i,b) row ----------------
__global__ __launch_bounds__(256)
void ln_kernel(const float* __restrict__ X, const float* __restrict__ gam,
               const float* __restrict__ bet, float* __restrict__ out) {
  const int row = blockIdx.x, t = threadIdx.x;
  const float4 x4 = *(const float4*)&X[(size_t)row * HIDN + t * 4];
  float s  = x4.x + x4.y + x4.z + x4.w;
  float sq = x4.x * x4.x + x4.y * x4.y + x4.z * x4.z + x4.w * x4.w;
#pragma unroll
  for (int o = 32; o >= 1; o >>= 1) { s += __shfl_xor(s, o); sq += __shfl_xor(sq, o); }
  __shared__ float red[8];
  const int wv = t >> 6;
  if ((t & 63) == 0) { red[wv * 2] = s; red[wv * 2 + 1] = sq; }
  __syncthreads();
  s  = red[0] + red[2] + red[4] + red[6];
  sq = red[1] + red[3] + red[5] + red[7];
  const float mu  = s * (1.f / HIDN);
  const float var = sq * (1.f / HIDN) - mu * mu;
  const float rs  = rsqrtf(var + LN_EPS);
  const float4 g4 = *(const float4*)&gam[t * 4];
  const float4 b4 = *(const float4*)&bet[t * 4];
  float4 o4;
  o4.x = (x4.x - mu) * rs * g4.x + b4.x;
  o4.y = (x4.y - mu) * rs * g4.y + b4.y;
  o4.z = (x4.z - mu) * rs * g4.z + b4.z;
  o4.w = (x4.w - mu) * rs * g4.w + b4.w;
  *(float4*)&out[(size_t)row * HIDN + t * 4] = o4;
}

extern "C" void kernel_launch(void* const* d_in, const int* in_sizes, int n_in,
                              void* d_out, int out_size, void* d_ws, size_t ws_size,
                              hipStream_t stream) {
  (void)in_sizes; (void)n_in; (void)out_size; (void)ws_size;
  const float* hidden = (const float*)d_in[0];
  const float* pos    = (const float*)d_in[1];
  const float* sege   = (const float*)d_in[2];
  const float* amask  = (const float*)d_in[3];
  const float* qw     = (const float*)d_in[4];
  const float* kw     = (const float*)d_in[5];
  const float* vw     = (const float*)d_in[6];
  const float* rw     = (const float*)d_in[7];
  const float* ow     = (const float*)d_in[8];
  const float* rwb    = (const float*)d_in[9];
  const float* rrb    = (const float*)d_in[10];
  const float* rsb    = (const float*)d_in[11];
  const float* segm   = (const float*)d_in[12];
  const float* gam    = (const float*)d_in[13];
  const float* bet    = (const float*)d_in[14];
  float* out = (float*)d_out;
  char* ws = (char*)d_ws;

  const size_t MiB = 1ull << 20;
  u16*   Wqt = (u16*)(ws);
  u16*   Wkt = (u16*)(ws + 2 * MiB);
  u16*   Wvt = (u16*)(ws + 4 * MiB);
  u16*   Wrt = (u16*)(ws + 6 * MiB);
  u16*   AOb = (u16*)(ws);
  u16*   Qh  = (u16*)(ws + 8 * MiB);
  u16*   Kf  = (u16*)(ws + 16 * MiB);
  u16*   Vf  = (u16*)(ws + 24 * MiB);
  u16*   Krf = (u16*)(ws + 32 * MiB);
  float* X   = (float*)(ws + 32 * MiB);
  u16*   Hb  = (u16*)(ws + 48 * MiB);
  u16*   SE4 = (u16*)(ws + 48 * MiB);
  u16*   MK  = (u16*)(ws + 56 * MiB);
  float* E   = (float*)(ws + 60 * MiB);
  u16*   Wob = (u16*)(ws + 60 * MiB + 512 * 1024);

  wtrans_kernel<<<dim3(16, 16, 4), 256, 0, stream>>>(qw, kw, vw, rw, Wqt, Wkt, Wvt, Wrt);
  hcvt_kernel<<<2560, 256, 0, stream>>>(hidden, ow, Hb, Wob);
  proj_gemm<<<1280, 256, 0, stream>>>(Hb, pos, Wqt, Wkt, Wvt, Wrt, Qh, Kf, Vf, Krf);
  vrepack_kernel<<<dim3(128, 8), 256, 0, stream>>>(Vf);
  setrans_kernel<<<dim3(512, 2), 256, 0, stream>>>(sege, amask, SE4, MK);
  seg_e_kernel<<<256, 256, 0, stream>>>(Qh, rsb, segm, E);
  attn_mfma<<<1024, 256, 0, stream>>>(Qh, Kf, Vf, Krf, E, SE4, MK, rwb, rrb, AOb);
  oproj_gemm<<<512, 256, 0, stream>>>(AOb, Wob, hidden, X);
  ln_kernel<<<4096, 256, 0, stream>>>(X, gam, bet, out);
}

// Round 14
// 159.677 us; speedup vs baseline: 1.5162x; 1.0346x over previous
//
#include <hip/hip_runtime.h>
#include <hip/hip_bf16.h>

#define I_LEN 512
#define BSZ   8
#define HIDN  1024
#define NHEAD 16
#define HDIM  64
#define PLEN_ 1024
#define SCALE_F 0.125f
#define BIGNUM 1e30f
#define LN_EPS 1e-5f

typedef unsigned int   u32;
typedef unsigned short u16;
typedef __attribute__((ext_vector_type(8))) short bf16x8;
typedef __attribute__((ext_vector_type(4))) float f32x4;

__device__ __forceinline__ float bflo(u32 w) { return __uint_as_float(w << 16); }
__device__ __forceinline__ float bfhi(u32 w) { return __uint_as_float(w & 0xffff0000u); }
__device__ __forceinline__ u16 f2bf(float x) {
  u32 u = __float_as_uint(x);
  return (u16)((u + 0x7fffu + ((u >> 16) & 1u)) >> 16);
}
__device__ __forceinline__ void bf8_to_f(const uint4 v, float* f) {
  f[0] = bflo(v.x); f[1] = bfhi(v.x);
  f[2] = bflo(v.y); f[3] = bfhi(v.y);
  f[4] = bflo(v.z); f[5] = bfhi(v.z);
  f[6] = bflo(v.w); f[7] = bfhi(v.w);
}

#define GLOAD_LDS16(gp, lp) __builtin_amdgcn_global_load_lds( \
    (const __attribute__((address_space(1))) void*)(gp),      \
    (__attribute__((address_space(3))) void*)(lp), 16, 0, 0)

// ---------------- fused projection GEMM: 5-way z, XCD-grouped, counted-vmcnt pipeline --
// z<3 (all-gload_lds): 2-buffer pipeline with s_waitcnt vmcnt(8) + raw barriers — the
// prefetch stays in flight across the barrier (T4). z>=3 (f32 reg-staged A): classic
// __syncthreads loop (cross-wave ds_write visibility kept on the proven path).
__global__ __launch_bounds__(256)
void proj_gemm(const u16* __restrict__ Hb, const float* __restrict__ pos,
               const u16* __restrict__ Wqt, const u16* __restrict__ Wkt,
               const u16* __restrict__ Wvt, const u16* __restrict__ Wrt,
               u16* __restrict__ Qh, u16* __restrict__ Kf,
               u16* __restrict__ Vh, u16* __restrict__ Krf) {
  constexpr int K = 1024;
  __shared__ union {
    struct { u16 As[2 * 8192]; u16 Bs[2 * 8192]; } st;  // 64 KB double-buffered staging
    u16 epi[4][64 * 68];                                 // per-wave head-contig epi
    u16 epiK[128 * 137];                                 // block-wide fragment epi
  } sm;
  u16* As = sm.st.As;
  u16* Bs = sm.st.Bs;
  // XCD-grouped decode
  const int id = blockIdx.x;
  const int low = id & 7;
  const int rest = id >> 3;
  const int bx = rest & 7;
  const int grp = low + 8 * (rest >> 3);   // 0..159
  const int by = grp & 31;
  const int z = grp >> 5;
  const u16* Bt; u16* C;
  if (z == 0)      { Bt = Wqt; C = Qh;  }
  else if (z == 1) { Bt = Wkt; C = Kf;  }
  else if (z == 2) { Bt = Wvt; C = Vh;  }
  else if (z == 3) { Bt = Wrt; C = Krf; }
  else             { Bt = Wrt; C = Krf; }
  const float* Apos = pos + (size_t)((z == 4) ? 4096 : 0) * 1024;
  const int bm = by * 128, bn = bx * 128;
  const int tid = threadIdx.x, wv = tid >> 6, lane = tid & 63;
  const int l15 = lane & 15, g = lane >> 4;
  const int wr = wv >> 1, wc = wv & 1;

#define STAGE_B_P(BUF, K0)                                                    \
  _Pragma("unroll")                                                           \
  for (int p = 0; p < 4; ++p) {                                               \
    const int unit = (wv * 4 + p) * 64 + lane;                                \
    const int row = unit >> 3, up = unit & 7, cc = up ^ (row & 7);            \
    GLOAD_LDS16(&Bt[(size_t)(bn + row) * K + (K0) + cc * 8],                  \
                &Bs[(BUF) * 8192 + unit * 8]);                                \
  }
#define STAGE_A16_P(BUF, K0)                                                  \
  _Pragma("unroll")                                                           \
  for (int p = 0; p < 4; ++p) {                                               \
    const int unit = (wv * 4 + p) * 64 + lane;                                \
    const int row = unit >> 3, up = unit & 7, cc = up ^ (row & 7);            \
    GLOAD_LDS16(&Hb[(size_t)(bm + row) * K + (K0) + cc * 8],                  \
                &As[(BUF) * 8192 + unit * 8]);                                \
  }
#define STAGE_A32_P(BUF, K0)                                                  \
  _Pragma("unroll")                                                           \
  for (int p = 0; p < 4; ++p) {                                               \
    const int unit = p * 256 + tid;                                           \
    const int row = unit >> 3, up = unit & 7, cc = up ^ (row & 7);            \
    const float* src = &Apos[(size_t)(bm + row) * K + (K0) + cc * 8];         \
    const float4 f0 = *(const float4*)src;                                    \
    const float4 f1 = *(const float4*)(src + 4);                              \
    ushort4 h0, h1;                                                           \
    h0.x = f2bf(f0.x); h0.y = f2bf(f0.y); h0.z = f2bf(f0.z); h0.w = f2bf(f0.w); \
    h1.x = f2bf(f1.x); h1.y = f2bf(f1.y); h1.z = f2bf(f1.z); h1.w = f2bf(f1.w); \
    *(ushort4*)&As[(BUF) * 8192 + unit * 8] = h0;                             \
    *(ushort4*)&As[(BUF) * 8192 + unit * 8 + 4] = h1;                         \
  }
#define COMPUTE_TILE(CUR)                                                     \
  {                                                                           \
    const u16* Ac = &As[(CUR) * 8192];                                        \
    const u16* Bc = &Bs[(CUR) * 8192];                                        \
    _Pragma("unroll")                                                         \
    for (int h = 0; h < 2; ++h) {                                             \
      bf16x8 af[4], bfv[4];                                                   \
      _Pragma("unroll")                                                       \
      for (int m = 0; m < 4; ++m) {                                           \
        const int row = wr * 64 + m * 16 + l15;                               \
        af[m] = *(const bf16x8*)&Ac[row * 64 + ((h * 4 + g) ^ (row & 7)) * 8];\
      }                                                                       \
      _Pragma("unroll")                                                       \
      for (int n = 0; n < 4; ++n) {                                           \
        const int col = wc * 64 + n * 16 + l15;                               \
        bfv[n] = *(const bf16x8*)&Bc[col * 64 + ((h * 4 + g) ^ (col & 7)) * 8];\
      }                                                                       \
      _Pragma("unroll")                                                       \
      for (int m = 0; m < 4; ++m)                                             \
        _Pragma("unroll")                                                     \
        for (int n = 0; n < 4; ++n)                                           \
          acc[m][n] = __builtin_amdgcn_mfma_f32_16x16x32_bf16(af[m], bfv[n],  \
                                                              acc[m][n], 0, 0, 0); \
    }                                                                         \
  }

  f32x4 acc[4][4];
#pragma unroll
  for (int m = 0; m < 4; ++m)
#pragma unroll
    for (int n = 0; n < 4; ++n) acc[m][n] = (f32x4){0.f, 0.f, 0.f, 0.f};

  if (z < 3) {
    // counted-vmcnt pipeline: 8 gload_lds/wave/iter stay in flight across barriers
    STAGE_B_P(0, 0);
    STAGE_A16_P(0, 0);
    int cur = 0;
    for (int t = 0; t < 16; ++t) {
      if (t < 15) {
        const int k1 = (t + 1) * 64;
        STAGE_B_P(cur ^ 1, k1);
        STAGE_A16_P(cur ^ 1, k1);
        asm volatile("s_waitcnt vmcnt(8)" ::: "memory");   // t's loads done; t+1's fly
      } else {
        asm volatile("s_waitcnt vmcnt(0)" ::: "memory");
      }
      __builtin_amdgcn_s_barrier();        // all waves' tile-t loads landed
      __builtin_amdgcn_sched_barrier(0);
      COMPUTE_TILE(cur);
      __builtin_amdgcn_s_barrier();        // all reads of cur done; safe to overwrite
      cur ^= 1;
    }
  } else {
    // reg-staged f32 A: proven drain loop
    STAGE_B_P(0, 0);
    STAGE_A32_P(0, 0);
    __syncthreads();
    int cur = 0;
    for (int t = 0; t < 16; ++t) {
      if (t < 15) {
        const int k1 = (t + 1) * 64;
        STAGE_B_P(cur ^ 1, k1);
        STAGE_A32_P(cur ^ 1, k1);
      }
      COMPUTE_TILE(cur);
      __syncthreads();
      cur ^= 1;
    }
  }

  if (z == 1 || z >= 3) {
    // fragment-major epilogue: block-wide 128x137 LDS tile, then 32 coalesced 1KB runs
    u16* E128 = sm.epiK;
#pragma unroll
    for (int m = 0; m < 4; ++m)
#pragma unroll
      for (int nf = 0; nf < 4; ++nf)
#pragma unroll
        for (int r = 0; r < 4; ++r)
          E128[(wr * 64 + m * 16 + g * 4 + r) * 137 + wc * 64 + nf * 16 + l15] =
              f2bf(acc[m][nf][r]);
    __syncthreads();
    const int tK = (z == 1) ? by : (by + ((z == 4) ? 32 : 0));
    const int TS = (z == 1) ? 32 : 64;
#pragma unroll
    for (int q = 0; q < 8; ++q) {
      const int rid = wv * 8 + q;
      const int n_loc = rid >> 4, b_ = (rid >> 1) & 7, h = rid & 1;
      union { u16 us[8]; uint4 qv; } o;
#pragma unroll
      for (int e = 0; e < 8; ++e)
        o.us[e] = E128[(l15 * 8 + b_) * 137 + n_loc * 64 + h * 32 + g * 8 + e];
      const int head = bx * 2 + n_loc;
      const size_t base = (((size_t)(b_ * 16 + head) * TS + tK) * 2 + h) * 512 + lane * 8;
      *(uint4*)&C[base] = o.qv;
    }
  } else {
    // head-contig epilogue (Q, V)
    u16* slice = sm.epi[wv];
    __syncthreads();
#pragma unroll
    for (int m = 0; m < 4; ++m)
#pragma unroll
      for (int nf = 0; nf < 4; ++nf)
#pragma unroll
        for (int r = 0; r < 4; ++r)
          slice[(m * 16 + g * 4 + r) * 68 + nf * 16 + l15] = f2bf(acc[m][nf][r]);
#pragma unroll
    for (int it = 0; it < 8; ++it) {
      const int rl = it * 8 + (lane >> 3);
      const int cl = (lane & 7) * 8;
      const ushort4 a = *(const ushort4*)&slice[rl * 68 + cl];
      const ushort4 b2 = *(const ushort4*)&slice[rl * 68 + cl + 4];
      const int row = bm + wr * 64 + rl;
      const int col = bn + wc * 64 + cl;
      const size_t idx = ((size_t)((row & 7) * 16 + (col >> 6)) * 512 + (row >> 3)) * 64 + (col & 63);
      *(ushort4*)&C[idx] = a;
      *(ushort4*)&C[idx + 4] = b2;
    }
  }
}

// ---------------- V repack (IN-PLACE): Vh[bn][j][d] -> Vf[bn][j64][c][h][lane][8] -------
__global__ __launch_bounds__(256)
void vrepack_kernel(u16* __restrict__ V) {
  __shared__ u16 tile[64][72];
  const int bn = blockIdx.x, slab = blockIdx.y;
  const int t = threadIdx.x;
  const size_t base = ((size_t)bn * 8 + slab) * 4096;
  {
    const int jl = t >> 2, c0 = (t & 3) * 16;
    const uint4 v0 = *(const uint4*)&V[base + jl * 64 + c0];
    const uint4 v1 = *(const uint4*)&V[base + jl * 64 + c0 + 8];
    *(uint4*)&tile[jl][c0] = v0;
    *(uint4*)&tile[jl][c0 + 8] = v1;
  }
  __syncthreads();
  const int lane = t & 63, g = lane >> 4, l15 = lane & 15;
#pragma unroll
  for (int w = 0; w < 2; ++w) {
    const int run = w * 4 + (t >> 6);
    const int c = run >> 1, h = run & 1;
    union { u16 us[8]; uint4 qv; } o;
#pragma unroll
    for (int e = 0; e < 8; ++e) o.us[e] = tile[h * 32 + g * 8 + e][16 * c + l15];
    *(uint4*)&V[base + run * 512 + lane * 8] = o.qv;
  }
}

// ---------------- hidden + ow f32 -> bf16 ----------------
__global__ __launch_bounds__(256)
void hcvt_kernel(const float* __restrict__ hidden, const float* __restrict__ ow,
                 u16* __restrict__ Hb, u16* __restrict__ Wob) {
  const size_t i = (size_t)blockIdx.x * 256 + threadIdx.x;
  const float* src; u16* dst; size_t off;
  if (i < 524288) { src = hidden; dst = Hb; off = i * 8; }
  else            { src = ow;     dst = Wob; off = (i - 524288) * 8; }
  const float4 a = *(const float4*)&src[off];
  const float4 b = *(const float4*)&src[off + 4];
  ushort4 o0, o1;
  o0.x = f2bf(a.x); o0.y = f2bf(a.y); o0.z = f2bf(a.z); o0.w = f2bf(a.w);
  o1.x = f2bf(b.x); o1.y = f2bf(b.y); o1.z = f2bf(b.z); o1.w = f2bf(b.w);
  *(ushort4*)&dst[off] = o0;
  *(ushort4*)&dst[off + 4] = o1;
}

// ---------------- weight transpose+cvt: W[h][nd] f32 -> T[nd][h] bf16 ----------------
__global__ __launch_bounds__(256)
void wtrans_kernel(const float* __restrict__ W0, const float* __restrict__ W1,
                   const float* __restrict__ W2, const float* __restrict__ W3,
                   u16* __restrict__ T0, u16* __restrict__ T1,
                   u16* __restrict__ T2, u16* __restrict__ T3) {
  __shared__ u16 tile[64][72];
  const int z = blockIdx.z;
  const float* W = (z == 0) ? W0 : ((z == 1) ? W1 : ((z == 2) ? W2 : W3));
  u16* T = (z == 0) ? T0 : ((z == 1) ? T1 : ((z == 2) ? T2 : T3));
  const int h0 = blockIdx.y * 64, nd0 = blockIdx.x * 64;
  const int t = threadIdx.x;
  {
    const int hr = t >> 2, c0 = (t & 3) * 16;
#pragma unroll
    for (int q = 0; q < 4; ++q) {
      const float4 f = *(const float4*)&W[(size_t)(h0 + hr) * 1024 + nd0 + c0 + q * 4];
      tile[hr][c0 + q * 4 + 0] = f2bf(f.x);
      tile[hr][c0 + q * 4 + 1] = f2bf(f.y);
      tile[hr][c0 + q * 4 + 2] = f2bf(f.z);
      tile[hr][c0 + q * 4 + 3] = f2bf(f.w);
    }
  }
  __syncthreads();
  const int ndr = t >> 2, hc0 = (t & 3) * 16;
  union { u16 us[16]; uint4 qv[2]; } o;
#pragma unroll
  for (int e = 0; e < 16; ++e) o.us[e] = tile[hc0 + e][ndr];
  uint4* dst = (uint4*)&T[(size_t)(nd0 + ndr) * 1024 + h0 + hc0];
  dst[0] = o.qv[0]; dst[1] = o.qv[1];
}

// -------- sege+mask transpose: SE4[b][i][j] packed 2xbf16; MK[b][i][j] bf16 BIG*mask ---
__global__ __launch_bounds__(256)
void setrans_kernel(const float* __restrict__ sege, const float* __restrict__ amask,
                    u16* __restrict__ SE4, u16* __restrict__ MK) {
  const int i = blockIdx.x;
  const int j = blockIdx.y * 256 + threadIdx.x;
  const float* sp = &sege[((size_t)i * 512 + j) * 16];
  const float* mp = &amask[((size_t)i * 512 + j) * 8];
  float se[16], mk[8];
#pragma unroll
  for (int q = 0; q < 4; ++q) {
    const float4 f = *(const float4*)(sp + q * 4);
    se[q * 4 + 0] = f.x; se[q * 4 + 1] = f.y; se[q * 4 + 2] = f.z; se[q * 4 + 3] = f.w;
  }
#pragma unroll
  for (int q = 0; q < 2; ++q) {
    const float4 f = *(const float4*)(mp + q * 4);
    mk[q * 4 + 0] = f.x; mk[q * 4 + 1] = f.y; mk[q * 4 + 2] = f.z; mk[q * 4 + 3] = f.w;
  }
#pragma unroll
  for (int b = 0; b < 8; ++b) {
    const u32 pk = (u32)f2bf(se[b * 2]) | ((u32)f2bf(se[b * 2 + 1]) << 16);
    const size_t plane = ((size_t)b * 512 + i) * 512 + j;
    *(u32*)&SE4[plane * 2] = pk;
    MK[plane] = f2bf(BIGNUM * mk[b]);
  }
}

// ---------------- e_s = (q + r_s_bias) . seg_mat[s], s in {0,1} ----------------
__global__ __launch_bounds__(256)
void seg_e_kernel(const u16* __restrict__ Qh, const float* __restrict__ rsb,
                  const float* __restrict__ segm, float* __restrict__ E) {
  const int gt = blockIdx.x * 256 + threadIdx.x;  // gt = (i*BSZ+b)*NHEAD + n
  const int i = gt >> 7, bb = (gt >> 4) & 7, n = gt & 15;
  const size_t base = (((size_t)bb * 16 + n) * 512 + i) * 64;
  float e0 = 0.f, e1 = 0.f;
#pragma unroll
  for (int u8 = 0; u8 < 8; ++u8) {
    const uint4 qv = *(const uint4*)&Qh[base + u8 * 8];
    float qf[8];
    bf8_to_f(qv, qf);
#pragma unroll
    for (int w = 0; w < 8; ++w) {
      const int d = u8 * 8 + w;
      const float q = qf[w] + rsb[n * HDIM + d];
      e0 += q * segm[n * HDIM + d];
      e1 += q * segm[HIDN + n * HDIM + d];
    }
  }
  E[(size_t)gt * 2 + 0] = e0;
  E[(size_t)gt * 2 + 1] = e1;
}

// ---------------- MFMA fused attention: fragment-major coalesced operands -------------
__global__ __launch_bounds__(256)
void attn_mfma(const u16* __restrict__ Qh, const u16* __restrict__ Kf,
               const u16* __restrict__ Vf, const u16* __restrict__ Krf,
               const float* __restrict__ E, const u16* __restrict__ SE4,
               const u16* __restrict__ MK, const float* __restrict__ rwb,
               const float* __restrict__ rrb, u16* __restrict__ AOb) {
  __shared__ u16 Pl[4][16 * 64];
  const int id = blockIdx.x;
  const int b = id & 7, n = (id >> 3) & 15;
  const int i0 = (id >> 7) * 64;
  const int bn = b * 16 + n;
  const int t = threadIdx.x, wv = t >> 6, lane = t & 63;
  const int l15 = lane & 15, g = lane >> 4;
  const int irow0 = i0 + wv * 16;
  u16* Pw = Pl[wv];
  const int bn64 = bn * 64;

  bf16x8 qcf[2], qrf[2];
#pragma unroll
  for (int h = 0; h < 2; ++h) {
    const int d0 = 32 * h + g * 8;
    const uint4 qv = *(const uint4*)&Qh[((size_t)bn * 512 + irow0 + l15) * 64 + d0];
    float qf[8]; bf8_to_f(qv, qf);
    union { u16 us[8]; bf16x8 v; } ua, ub;
#pragma unroll
    for (int w = 0; w < 8; ++w) {
      ua.us[w] = f2bf((qf[w] + rwb[n * HDIM + d0 + w]) * SCALE_F);
      ub.us[w] = f2bf((qf[w] + rrb[n * HDIM + d0 + w]) * SCALE_F);
    }
    qcf[h] = ua.v; qrf[h] = ub.v;
  }

  float e0v[4], e1v[4], lrun[4];
  f32x4 accO[4];
#pragma unroll
  for (int r = 0; r < 4; ++r) {
    const int i = irow0 + 4 * g + r;
    const float2 ee = *(const float2*)&E[((size_t)(i * BSZ + b) * NHEAD + n) * 2];
    e0v[r] = ee.x * SCALE_F; e1v[r] = ee.y * SCALE_F;
    lrun[r] = 0.f;
  }
#pragma unroll
  for (int c = 0; c < 4; ++c) accO[c] = (f32x4){0.f, 0.f, 0.f, 0.f};

  for (int jb = 0; jb < I_LEN; jb += 64) {
    u32 sev[4][4]; u16 mkv[4][4];
#pragma unroll
    for (int c = 0; c < 4; ++c)
#pragma unroll
      for (int r = 0; r < 4; ++r) {
        const size_t plane = ((size_t)b * 512 + (irow0 + 4 * g + r)) * 512 + jb + 16 * c + l15;
        sev[c][r] = *(const u32*)&SE4[plane * 2];
        mkv[c][r] = MK[plane];
      }
    bf16x8 vf[4][2];
#pragma unroll
    for (int c = 0; c < 4; ++c) {
      const u16* vp = &Vf[((((size_t)bn * 8 + (jb >> 6)) * 4 + c) * 2) * 512 + lane * 8];
      vf[c][0] = *(const bf16x8*)vp;
      vf[c][1] = *(const bf16x8*)(vp + 512);
    }
    f32x4 S[4];
#pragma unroll
    for (int c = 0; c < 4; ++c) S[c] = (f32x4){0.f, 0.f, 0.f, 0.f};
#pragma unroll
    for (int c = 0; c < 4; ++c) {
      const u16* kp = &Kf[(((size_t)bn * 32 + (jb >> 4) + c) * 2) * 512 + lane * 8];
      S[c] = __builtin_amdgcn_mfma_f32_16x16x32_bf16(qcf[0], *(const bf16x8*)kp, S[c], 0, 0, 0);
      S[c] = __builtin_amdgcn_mfma_f32_16x16x32_bf16(qcf[1], *(const bf16x8*)(kp + 512), S[c], 0, 0, 0);
    }
    const int tb = (jb + 496 - irow0) >> 4;
    f32x4 T[5];
#pragma unroll
    for (int c = 0; c < 5; ++c) T[c] = (f32x4){0.f, 0.f, 0.f, 0.f};
#pragma unroll
    for (int c = 0; c < 5; ++c) {
      const u16* kp = &Krf[(((size_t)bn * 64 + tb + c) * 2) * 512 + lane * 8];
      T[c] = __builtin_amdgcn_mfma_f32_16x16x32_bf16(qrf[0], *(const bf16x8*)kp, T[c], 0, 0, 0);
      T[c] = __builtin_amdgcn_mfma_f32_16x16x32_bf16(qrf[1], *(const bf16x8*)(kp + 512), T[c], 0, 0, 0);
    }
    float bd[4][4];
#pragma unroll
    for (int r = 0; r < 4; ++r) {
      const int ii = 4 * g + r;
      const int pos = (lane & 48) | ((l15 - ii) & 15);
      float bp[5];
#pragma unroll
      for (int c = 0; c < 5; ++c) bp[c] = __shfl(T[c][r], pos, 64);
      const bool sel = l15 >= ii;
#pragma unroll
      for (int c = 0; c < 4; ++c) bd[c][r] = sel ? bp[c + 1] : bp[c];
    }
#pragma unroll
    for (int c = 0; c < 4; ++c)
#pragma unroll
      for (int r = 0; r < 4; ++r) {
        const u32 sev_ = sev[c][r];
        const float s = S[c][r] + bd[c][r] + bflo(sev_) * e0v[r] + bfhi(sev_) * e1v[r]
                        - bflo((u32)mkv[c][r]);
        const float p = __expf(s);
        S[c][r] = p;
        lrun[r] += p;
      }
#pragma unroll
    for (int c = 0; c < 4; ++c)
#pragma unroll
      for (int r = 0; r < 4; ++r) {
        const int ii = 4 * g + r;
        Pw[ii * 64 + ((16 * c + l15) ^ ((ii & 7) << 3))] = f2bf(S[c][r]);
      }
    const bf16x8 pa0 = *(const bf16x8*)&Pw[l15 * 64 + ((g * 8) ^ ((l15 & 7) << 3))];
    const bf16x8 pa1 = *(const bf16x8*)&Pw[l15 * 64 + ((32 + g * 8) ^ ((l15 & 7) << 3))];
#pragma unroll
    for (int c = 0; c < 4; ++c) {
      accO[c] = __builtin_amdgcn_mfma_f32_16x16x32_bf16(pa0, vf[c][0], accO[c], 0, 0, 0);
      accO[c] = __builtin_amdgcn_mfma_f32_16x16x32_bf16(pa1, vf[c][1], accO[c], 0, 0, 0);
    }
  }
#pragma unroll
  for (int r = 0; r < 4; ++r) {
#pragma unroll
    for (int o = 1; o < 16; o <<= 1) lrun[r] += __shfl_xor(lrun[r], o);
  }
#pragma unroll
  for (int c = 0; c < 4; ++c)
#pragma unroll
    for (int r = 0; r < 4; ++r) {
      const int ii = 4 * g + r;
      AOb[(size_t)(irow0 + ii) * 8192 + bn64 + 16 * c + l15] = f2bf(accO[c][r] / lrun[r]);
    }
}

// ---------------- O-projection GEMM: XCD-grouped, counted-vmcnt pipeline ----------------
__global__ __launch_bounds__(256)
void oproj_gemm(const u16* __restrict__ A, const u16* __restrict__ Wob,
                const float* __restrict__ Res, float* __restrict__ C) {
  constexpr int K = 1024;
  __shared__ u16 As[2 * 4096];
  __shared__ u16 Bs[2 * 8192];
  const int id = blockIdx.x;
  const int low = id & 7;
  const int rest = id >> 3;
  const int bx = rest & 7;
  const int by = low + 8 * (rest >> 3);    // 0..63
  const int bm = by * 64, bn = bx * 128;
  const int tid = threadIdx.x, wv = tid >> 6, lane = tid & 63;
  const int l15 = lane & 15, g = lane >> 4;
  const int wr = wv >> 1, wc = wv & 1;

#define STAGE_O(BUF, K0)                                                      \
  _Pragma("unroll")                                                           \
  for (int p = 0; p < 2; ++p) {                                               \
    const int unit = (wv * 2 + p) * 64 + lane;                                \
    const int row = unit >> 3, up = unit & 7, cc = up ^ (row & 7);            \
    GLOAD_LDS16(&A[(size_t)(bm + row) * K + (K0) + cc * 8],                   \
                &As[(BUF) * 4096 + unit * 8]);                                \
  }                                                                           \
  _Pragma("unroll")                                                           \
  for (int p = 0; p < 4; ++p) {                                               \
    const int unit = (wv * 4 + p) * 64 + lane;                                \
    const int row = unit >> 3, up = unit & 7, cc = up ^ (row & 7);            \
    GLOAD_LDS16(&Wob[(size_t)(bn + row) * K + (K0) + cc * 8],                 \
                &Bs[(BUF) * 8192 + unit * 8]);                                \
  }

  f32x4 acc[2][4];
#pragma unroll
  for (int m = 0; m < 2; ++m)
#pragma unroll
    for (int n = 0; n < 4; ++n) acc[m][n] = (f32x4){0.f, 0.f, 0.f, 0.f};

  STAGE_O(0, 0);
  int cur = 0;
  for (int t = 0; t < 16; ++t) {
    if (t < 15) {
      STAGE_O(cur ^ 1, (t + 1) * 64);
      asm volatile("s_waitcnt vmcnt(6)" ::: "memory");
    } else {
      asm volatile("s_waitcnt vmcnt(0)" ::: "memory");
    }
    __builtin_amdgcn_s_barrier();
    __builtin_amdgcn_sched_barrier(0);
    const u16* Ac = &As[cur * 4096];
    const u16* Bc = &Bs[cur * 8192];
#pragma unroll
    for (int h = 0; h < 2; ++h) {
      bf16x8 af[2], bfv[4];
#pragma unroll
      for (int m = 0; m < 2; ++m) {
        const int row = wr * 32 + m * 16 + l15;
        af[m] = *(const bf16x8*)&Ac[row * 64 + ((h * 4 + g) ^ (row & 7)) * 8];
      }
#pragma unroll
      for (int n = 0; n < 4; ++n) {
        const int col = wc * 64 + n * 16 + l15;
        bfv[n] = *(const bf16x8*)&Bc[col * 64 + ((h * 4 + g) ^ (col & 7)) * 8];
      }
#pragma unroll
      for (int m = 0; m < 2; ++m)
#pragma unroll
        for (int n = 0; n < 4; ++n)
          acc[m][n] = __builtin_amdgcn_mfma_f32_16x16x32_bf16(af[m], bfv[n], acc[m][n], 0, 0, 0);
    }
    __builtin_amdgcn_s_barrier();
    cur ^= 1;
  }
#pragma unroll
  for (int m = 0; m < 2; ++m) {
    const int row0 = bm + wr * 32 + m * 16 + g * 4;
#pragma unroll
    for (int nf = 0; nf < 4; ++nf) {
      const int col = bn + wc * 64 + nf * 16 + l15;
#pragma unroll
      for (int r = 0; r < 4; ++r) {
        const int row = row0 + r;
        C[(size_t)row * 1024 + col] = acc[m][nf][r] + Res[(size_t)row * 1024 + col];
      }
    }
  }
}

// ---------------- LayerNorm over HID=1024, one block per (i,b) row ----------------
__global__ __launch_bounds__(256)
void ln_kernel(const float* __restrict__ X, const float* __restrict__ gam,
               const float* __restrict__ bet, float* __restrict__ out) {
  const int row = blockIdx.x, t = threadIdx.x;
  const float4 x4 = *(const float4*)&X[(size_t)row * HIDN + t * 4];
  float s  = x4.x + x4.y + x4.z + x4.w;
  float sq = x4.x * x4.x + x4.y * x4.y + x4.z * x4.z + x4.w * x4.w;
#pragma unroll
  for (int o = 32; o >= 1; o >>= 1) { s += __shfl_xor(s, o); sq += __shfl_xor(sq, o); }
  __shared__ float red[8];
  const int wv = t >> 6;
  if ((t & 63) == 0) { red[wv * 2] = s; red[wv * 2 + 1] = sq; }
  __syncthreads();
  s  = red[0] + red[2] + red[4] + red[6];
  sq = red[1] + red[3] + red[5] + red[7];
  const float mu  = s * (1.f / HIDN);
  const float var = sq * (1.f / HIDN) - mu * mu;
  const float rs  = rsqrtf(var + LN_EPS);
  const float4 g4 = *(const float4*)&gam[t * 4];
  const float4 b4 = *(const float4*)&bet[t * 4];
  float4 o4;
  o4.x = (x4.x - mu) * rs * g4.x + b4.x;
  o4.y = (x4.y - mu) * rs * g4.y + b4.y;
  o4.z = (x4.z - mu) * rs * g4.z + b4.z;
  o4.w = (x4.w - mu) * rs * g4.w + b4.w;
  *(float4*)&out[(size_t)row * HIDN + t * 4] = o4;
}

extern "C" void kernel_launch(void* const* d_in, const int* in_sizes, int n_in,
                              void* d_out, int out_size, void* d_ws, size_t ws_size,
                              hipStream_t stream) {
  (void)in_sizes; (void)n_in; (void)out_size; (void)ws_size;
  const float* hidden = (const float*)d_in[0];
  const float* pos    = (const float*)d_in[1];
  const float* sege   = (const float*)d_in[2];
  const float* amask  = (const float*)d_in[3];
  const float* qw     = (const float*)d_in[4];
  const float* kw     = (const float*)d_in[5];
  const float* vw     = (const float*)d_in[6];
  const float* rw     = (const float*)d_in[7];
  const float* ow     = (const float*)d_in[8];
  const float* rwb    = (const float*)d_in[9];
  const float* rrb    = (const float*)d_in[10];
  const float* rsb    = (const float*)d_in[11];
  const float* segm   = (const float*)d_in[12];
  const float* gam    = (const float*)d_in[13];
  const float* bet    = (const float*)d_in[14];
  float* out = (float*)d_out;
  char* ws = (char*)d_ws;

  const size_t MiB = 1ull << 20;
  u16*   Wqt = (u16*)(ws);
  u16*   Wkt = (u16*)(ws + 2 * MiB);
  u16*   Wvt = (u16*)(ws + 4 * MiB);
  u16*   Wrt = (u16*)(ws + 6 * MiB);
  u16*   AOb = (u16*)(ws);
  u16*   Qh  = (u16*)(ws + 8 * MiB);
  u16*   Kf  = (u16*)(ws + 16 * MiB);
  u16*   Vf  = (u16*)(ws + 24 * MiB);
  u16*   Krf = (u16*)(ws + 32 * MiB);
  float* X   = (float*)(ws + 32 * MiB);
  u16*   Hb  = (u16*)(ws + 48 * MiB);
  u16*   SE4 = (u16*)(ws + 48 * MiB);
  u16*   MK  = (u16*)(ws + 56 * MiB);
  float* E   = (float*)(ws + 60 * MiB);
  u16*   Wob = (u16*)(ws + 60 * MiB + 512 * 1024);

  wtrans_kernel<<<dim3(16, 16, 4), 256, 0, stream>>>(qw, kw, vw, rw, Wqt, Wkt, Wvt, Wrt);
  hcvt_kernel<<<2560, 256, 0, stream>>>(hidden, ow, Hb, Wob);
  proj_gemm<<<1280, 256, 0, stream>>>(Hb, pos, Wqt, Wkt, Wvt, Wrt, Qh, Kf, Vf, Krf);
  vrepack_kernel<<<dim3(128, 8), 256, 0, stream>>>(Vf);
  setrans_kernel<<<dim3(512, 2), 256, 0, stream>>>(sege, amask, SE4, MK);
  seg_e_kernel<<<256, 256, 0, stream>>>(Qh, rsb, segm, E);
  attn_mfma<<<1024, 256, 0, stream>>>(Qh, Kf, Vf, Krf, E, SE4, MK, rwb, rrb, AOb);
  oproj_gemm<<<512, 256, 0, stream>>>(AOb, Wob, hidden, X);
  ln_kernel<<<4096, 256, 0, stream>>>(X, gam, bet, out);
}